// Round 1
// baseline (347.640 us; speedup 1.0000x reference)
//
#include <hip/hip_runtime.h>
#include <hip/hip_bf16.h>
#include <stdint.h>

typedef __bf16 bf16x8 __attribute__((ext_vector_type(8)));
typedef float f32x4 __attribute__((ext_vector_type(4)));

#define ROUTE_BIAS_F 10.0f
#define VOCAB_SZ 32000

// ---------- helpers ----------
__device__ __forceinline__ unsigned short f2bf(float f) {
    union { float f; unsigned u; } v; v.f = f;
    unsigned u = v.u;
    unsigned r = u + 0x7FFFu + ((u >> 16) & 1u);   // RNE
    return (unsigned short)(r >> 16);
}
__device__ __forceinline__ float bf2f(unsigned short s) {
    union { unsigned u; float f; } v; v.u = ((unsigned)s) << 16;
    return v.f;
}

// ---------- fp32 -> bf16 elementwise convert ----------
__global__ void k_convert_bf16(const float* __restrict__ in,
                               unsigned short* __restrict__ out, int n) {
    int i = (blockIdx.x * blockDim.x + threadIdx.x) * 4;
    if (i + 3 < n) {
        float4 f = *(const float4*)(in + i);
        ushort4 o;
        o.x = f2bf(f.x); o.y = f2bf(f.y); o.z = f2bf(f.z); o.w = f2bf(f.w);
        *(ushort4*)(out + i) = o;
    } else {
        for (; i < n; ++i) out[i] = f2bf(in[i]);
    }
}

// ---------- per-expert transpose + convert: in[R][C] fp32 -> out[C][R] bf16 ----------
__global__ void k_transpose_bf16(const float* __restrict__ in,
                                 unsigned short* __restrict__ out, int R, int C) {
    __shared__ float tile[32][33];
    int e = blockIdx.z;
    const float* inp = in + (size_t)e * R * C;
    unsigned short* outp = out + (size_t)e * R * C;
    int c0 = blockIdx.x * 32, r0 = blockIdx.y * 32;
    int tx = threadIdx.x, ty = threadIdx.y;   // 32 x 8
#pragma unroll
    for (int k = 0; k < 32; k += 8)
        tile[ty + k][tx] = inp[(size_t)(r0 + ty + k) * C + c0 + tx];
    __syncthreads();
#pragma unroll
    for (int k = 0; k < 32; k += 8)
        outp[(size_t)(c0 + ty + k) * R + r0 + tx] = f2bf(tile[tx][ty + k]);
}

// ---------- router: fp32 logits, argmax with bias, bucket tokens ----------
__global__ void k_router(const float* __restrict__ mu, const int* __restrict__ tok_ids,
                         const float* __restrict__ rw, int H, int N,
                         int* __restrict__ counts, int* __restrict__ list) {
    int tok = blockIdx.x;
    int lane = threadIdx.x;   // 64 threads = 1 wave
    float acc[8];
#pragma unroll
    for (int e = 0; e < 8; ++e) acc[e] = 0.f;
    const float* m = mu + (size_t)tok * H;
    for (int h = lane; h < H; h += 64) {
        float mv = m[h];
#pragma unroll
        for (int e = 0; e < 8; ++e) acc[e] += mv * rw[e * H + h];
    }
#pragma unroll
    for (int e = 0; e < 8; ++e) {
        float v = acc[e];
        for (int off = 32; off > 0; off >>= 1) v += __shfl_down(v, off);
        acc[e] = v;
    }
    if (lane == 0) {
        int t = tok_ids[tok];
        if (t < 0) t = 0;
        if (t > VOCAB_SZ - 1) t = VOCAB_SZ - 1;
        int be = t % 8;
        float best = -1e30f; int bi = 0;
#pragma unroll
        for (int e = 0; e < 8; ++e) {
            float v = acc[e] + (e == be ? ROUTE_BIAS_F : 0.f);
            if (v > best) { best = v; bi = e; }
        }
        int pos = atomicAdd(&counts[bi], 1);
        list[bi * N + pos] = tok;
    }
}

__global__ void k_prefix(const int* __restrict__ counts, int* __restrict__ base_, int E) {
    if (threadIdx.x == 0 && blockIdx.x == 0) {
        int s = 0;
        for (int e = 0; e < E; ++e) { base_[e] = s; s += counts[e]; }
    }
}

// ---------- GEMM tile constants ----------
#define TM 128
#define TN 128
#define TK 64
#define LDSP 72   // padded LDS row length (bf16 elems): 144B rows -> clean bank spread

// GEMM1: GU[compact_row][F2] = gather(X)[token][H] @ Wt[e][F2][H]^T  (Wt is f-major)
__global__ __launch_bounds__(256, 2) void k_gemm_gateup(
    const unsigned short* __restrict__ X,    // [N][H] bf16
    const unsigned short* __restrict__ Wt,   // [E][F2][H] bf16
    unsigned short* __restrict__ GU,         // [N][F2] bf16 compact rows
    const int* __restrict__ counts, const int* __restrict__ base_,
    const int* __restrict__ list, int N, int H, int F2) {
    int e = blockIdx.z, mt = blockIdx.y, nt = blockIdx.x;
    int cnt = counts[e];
    int m0 = mt * TM;
    if (m0 >= cnt) return;
    int n0 = nt * TN;

    __shared__ __align__(16) unsigned short As[TM * LDSP];
    __shared__ __align__(16) unsigned short Bs[TN * LDSP];

    int tid = threadIdx.x;
    int lane = tid & 63, wid = tid >> 6;
    int wm = (wid >> 1) * 64, wn = (wid & 1) * 64;

    f32x4 acc[4][4];
#pragma unroll
    for (int i = 0; i < 4; ++i)
#pragma unroll
        for (int j = 0; j < 4; ++j) acc[i][j] = (f32x4)(0.f);

    const unsigned short* We = Wt + ((size_t)e * F2 + n0) * H;

    const unsigned short* aptr[4];
#pragma unroll
    for (int i = 0; i < 4; ++i) {
        int chunk = tid + 256 * i;
        int r = chunk >> 3;
        int gr = m0 + r;
        aptr[i] = (gr < cnt) ? X + (size_t)list[e * N + gr] * H : nullptr;
    }

    for (int k0 = 0; k0 < H; k0 += TK) {
#pragma unroll
        for (int i = 0; i < 4; ++i) {
            int chunk = tid + 256 * i;
            int r = chunk >> 3, cc = (chunk & 7) * 8;
            uint4 v = make_uint4(0u, 0u, 0u, 0u);
            if (aptr[i]) v = *(const uint4*)(aptr[i] + k0 + cc);
            *(uint4*)&As[r * LDSP + cc] = v;
        }
#pragma unroll
        for (int i = 0; i < 4; ++i) {
            int chunk = tid + 256 * i;
            int r = chunk >> 3, cc = (chunk & 7) * 8;
            uint4 v = *(const uint4*)(We + (size_t)r * H + k0 + cc);
            *(uint4*)&Bs[r * LDSP + cc] = v;
        }
        __syncthreads();
#pragma unroll
        for (int ks = 0; ks < TK; ks += 32) {
            bf16x8 af[4], bfr[4];
            int kk = ks + (lane >> 4) * 8;
            int rA = wm + (lane & 15);
            int rB = wn + (lane & 15);
#pragma unroll
            for (int im = 0; im < 4; ++im)
                af[im] = *(const bf16x8*)&As[(rA + im * 16) * LDSP + kk];
#pragma unroll
            for (int in_ = 0; in_ < 4; ++in_)
                bfr[in_] = *(const bf16x8*)&Bs[(rB + in_ * 16) * LDSP + kk];
#pragma unroll
            for (int im = 0; im < 4; ++im)
#pragma unroll
                for (int in_ = 0; in_ < 4; ++in_)
                    acc[im][in_] = __builtin_amdgcn_mfma_f32_16x16x32_bf16(
                        af[im], bfr[in_], acc[im][in_], 0, 0, 0);
        }
        __syncthreads();
    }

    int b = base_[e];
#pragma unroll
    for (int im = 0; im < 4; ++im) {
#pragma unroll
        for (int j = 0; j < 4; ++j) {
            int row = wm + im * 16 + (lane >> 4) * 4 + j;
            int gr = m0 + row;
            if (gr < cnt) {
                unsigned short* orow = GU + (size_t)(b + gr) * F2 + n0;
#pragma unroll
                for (int in_ = 0; in_ < 4; ++in_) {
                    int col = wn + in_ * 16 + (lane & 15);
                    orow[col] = f2bf(acc[im][in_][j]);
                }
            }
        }
    }
}

// ---------- silu(gate)*up over compact rows ----------
__global__ void k_silu(const unsigned short* __restrict__ GU,
                       unsigned short* __restrict__ IT, int N, int Ie) {
    int idx = blockIdx.x * blockDim.x + threadIdx.x;
    if (idx >= N * Ie) return;
    int r = idx / Ie, c = idx - r * Ie;
    float g = bf2f(GU[(size_t)r * 2 * Ie + c]);
    float u = bf2f(GU[(size_t)r * 2 * Ie + Ie + c]);
    float s = g / (1.f + __expf(-g));
    IT[idx] = f2bf(s * u);
}

// GEMM2: OUT[token][H] = IT[compact_row][Ie] @ Wt[e][H][Ie]^T, rows scattered by list
__global__ __launch_bounds__(256, 2) void k_gemm_down(
    const unsigned short* __restrict__ IT,   // [N][Ie] bf16 compact
    const unsigned short* __restrict__ Wt,   // [E][H][Ie] bf16
    float* __restrict__ OUT,                 // [N][H] fp32 token-order
    const int* __restrict__ counts, const int* __restrict__ base_,
    const int* __restrict__ list, int N, int Ie, int H) {
    int e = blockIdx.z, mt = blockIdx.y, nt = blockIdx.x;
    int cnt = counts[e];
    int m0 = mt * TM;
    if (m0 >= cnt) return;
    int n0 = nt * TN;
    int b = base_[e];

    __shared__ __align__(16) unsigned short As[TM * LDSP];
    __shared__ __align__(16) unsigned short Bs[TN * LDSP];

    int tid = threadIdx.x;
    int lane = tid & 63, wid = tid >> 6;
    int wm = (wid >> 1) * 64, wn = (wid & 1) * 64;

    f32x4 acc[4][4];
#pragma unroll
    for (int i = 0; i < 4; ++i)
#pragma unroll
        for (int j = 0; j < 4; ++j) acc[i][j] = (f32x4)(0.f);

    const unsigned short* We = Wt + ((size_t)e * H + n0) * Ie;

    const unsigned short* aptr[4];
#pragma unroll
    for (int i = 0; i < 4; ++i) {
        int chunk = tid + 256 * i;
        int r = chunk >> 3;
        int gr = m0 + r;
        aptr[i] = (gr < cnt) ? IT + (size_t)(b + gr) * Ie : nullptr;
    }

    for (int k0 = 0; k0 < Ie; k0 += TK) {
#pragma unroll
        for (int i = 0; i < 4; ++i) {
            int chunk = tid + 256 * i;
            int r = chunk >> 3, cc = (chunk & 7) * 8;
            uint4 v = make_uint4(0u, 0u, 0u, 0u);
            if (aptr[i]) v = *(const uint4*)(aptr[i] + k0 + cc);
            *(uint4*)&As[r * LDSP + cc] = v;
        }
#pragma unroll
        for (int i = 0; i < 4; ++i) {
            int chunk = tid + 256 * i;
            int r = chunk >> 3, cc = (chunk & 7) * 8;
            uint4 v = *(const uint4*)(We + (size_t)r * Ie + k0 + cc);
            *(uint4*)&Bs[r * LDSP + cc] = v;
        }
        __syncthreads();
#pragma unroll
        for (int ks = 0; ks < TK; ks += 32) {
            bf16x8 af[4], bfr[4];
            int kk = ks + (lane >> 4) * 8;
            int rA = wm + (lane & 15);
            int rB = wn + (lane & 15);
#pragma unroll
            for (int im = 0; im < 4; ++im)
                af[im] = *(const bf16x8*)&As[(rA + im * 16) * LDSP + kk];
#pragma unroll
            for (int in_ = 0; in_ < 4; ++in_)
                bfr[in_] = *(const bf16x8*)&Bs[(rB + in_ * 16) * LDSP + kk];
#pragma unroll
            for (int im = 0; im < 4; ++im)
#pragma unroll
                for (int in_ = 0; in_ < 4; ++in_)
                    acc[im][in_] = __builtin_amdgcn_mfma_f32_16x16x32_bf16(
                        af[im], bfr[in_], acc[im][in_], 0, 0, 0);
        }
        __syncthreads();
    }

#pragma unroll
    for (int im = 0; im < 4; ++im) {
#pragma unroll
        for (int j = 0; j < 4; ++j) {
            int row = wm + im * 16 + (lane >> 4) * 4 + j;
            int gr = m0 + row;
            if (gr < cnt) {
                int tok = list[e * N + gr];
                float* orow = OUT + (size_t)tok * H + n0;
#pragma unroll
                for (int in_ = 0; in_ < 4; ++in_) {
                    int col = wn + in_ * 16 + (lane & 15);
                    orow[col] = acc[im][in_][j];
                }
            }
        }
    }
}

extern "C" void kernel_launch(void* const* d_in, const int* in_sizes, int n_in,
                              void* d_out, int out_size, void* d_ws, size_t ws_size,
                              hipStream_t stream) {
    const float* hidden   = (const float*)d_in[0];
    const int*   tok_ids  = (const int*)d_in[1];
    const float* mu       = (const float*)d_in[2];
    const float* gup      = (const float*)d_in[3];
    const float* dnp      = (const float*)d_in[4];
    const float* rw       = (const float*)d_in[5];
    float* out = (float*)d_out;

    int N  = in_sizes[1];                 // 8192
    int H  = in_sizes[0] / N;             // 1024
    int E  = in_sizes[5] / H;             // 8
    int F2 = in_sizes[3] / (E * H);       // 1024
    int Ie = F2 / 2;                      // 512

    char* ws = (char*)d_ws;
    size_t o = 0;
    auto alloc = [&](size_t sz) {
        size_t r = o;
        o += (sz + 255) & ~(size_t)255;
        return r;
    };
    int* counts = (int*)(ws + alloc((size_t)E * 4));
    int* base_  = (int*)(ws + alloc((size_t)E * 4));
    int* list   = (int*)(ws + alloc((size_t)E * N * 4));
    unsigned short* xb   = (unsigned short*)(ws + alloc((size_t)N * H * 2));
    unsigned short* wgut = (unsigned short*)(ws + alloc((size_t)E * F2 * H * 2));
    unsigned short* wdnt = (unsigned short*)(ws + alloc((size_t)E * H * Ie * 2));
    unsigned short* gu   = (unsigned short*)(ws + alloc((size_t)N * F2 * 2));
    unsigned short* inter = xb;   // alias: xb dead after GEMM1, inter (8MB) fits in xb (16MB)

    hipMemsetAsync(counts, 0, (size_t)E * 4, stream);

    k_convert_bf16<<<dim3((N * H / 4 + 255) / 256), dim3(256), 0, stream>>>(hidden, xb, N * H);

    dim3 tb(32, 8);
    k_transpose_bf16<<<dim3(F2 / 32, H / 32, E), tb, 0, stream>>>(gup, wgut, H, F2);
    k_transpose_bf16<<<dim3(H / 32, Ie / 32, E), tb, 0, stream>>>(dnp, wdnt, Ie, H);

    k_router<<<dim3(N), dim3(64), 0, stream>>>(mu, tok_ids, rw, H, N, counts, list);
    k_prefix<<<dim3(1), dim3(1), 0, stream>>>(counts, base_, E);

    dim3 g1(F2 / TN, (N + TM - 1) / TM, E);
    k_gemm_gateup<<<g1, dim3(256), 0, stream>>>(xb, wgut, gu, counts, base_, list, N, H, F2);

    k_silu<<<dim3((N * Ie + 255) / 256), dim3(256), 0, stream>>>(gu, inter, N, Ie);

    dim3 g2(H / TN, (N + TM - 1) / TM, E);
    k_gemm_down<<<g2, dim3(256), 0, stream>>>(inter, wdnt, out, counts, base_, list, N, Ie, H);
}

// Round 2
// 331.454 us; speedup vs baseline: 1.0488x; 1.0488x over previous
//
#include <hip/hip_runtime.h>
#include <hip/hip_bf16.h>
#include <stdint.h>

typedef __bf16 bf16x8 __attribute__((ext_vector_type(8)));
typedef float f32x4 __attribute__((ext_vector_type(4)));

#define ROUTE_BIAS_F 10.0f
#define VOCAB_SZ 32000

// ---------- helpers ----------
__device__ __forceinline__ unsigned short f2bf(float f) {
    union { float f; unsigned u; } v; v.f = f;
    unsigned u = v.u;
    unsigned r = u + 0x7FFFu + ((u >> 16) & 1u);   // RNE
    return (unsigned short)(r >> 16);
}
__device__ __forceinline__ float bf2f(unsigned short s) {
    union { unsigned u; float f; } v; v.u = ((unsigned)s) << 16;
    return v.f;
}

// ---------- fp32 -> bf16 elementwise convert ----------
__global__ void k_convert_bf16(const float* __restrict__ in,
                               unsigned short* __restrict__ out, int n) {
    int i = (blockIdx.x * blockDim.x + threadIdx.x) * 4;
    if (i + 3 < n) {
        float4 f = *(const float4*)(in + i);
        ushort4 o;
        o.x = f2bf(f.x); o.y = f2bf(f.y); o.z = f2bf(f.z); o.w = f2bf(f.w);
        *(ushort4*)(out + i) = o;
    } else {
        for (; i < n; ++i) out[i] = f2bf(in[i]);
    }
}

// ---------- per-expert transpose + convert: in[R][C] fp32 -> out[C][R] bf16 ----------
__global__ void k_transpose_bf16(const float* __restrict__ in,
                                 unsigned short* __restrict__ out, int R, int C) {
    __shared__ float tile[32][33];
    int e = blockIdx.z;
    const float* inp = in + (size_t)e * R * C;
    unsigned short* outp = out + (size_t)e * R * C;
    int c0 = blockIdx.x * 32, r0 = blockIdx.y * 32;
    int tx = threadIdx.x, ty = threadIdx.y;   // 32 x 8
#pragma unroll
    for (int k = 0; k < 32; k += 8)
        tile[ty + k][tx] = inp[(size_t)(r0 + ty + k) * C + c0 + tx];
    __syncthreads();
#pragma unroll
    for (int k = 0; k < 32; k += 8)
        outp[(size_t)(c0 + ty + k) * R + r0 + tx] = f2bf(tile[tx][ty + k]);
}

// ---------- router phase A: fp32 logits + biased argmax, NO atomics ----------
// 256 threads = 4 waves; each wave computes one token's 8 logits.
__global__ void k_logits(const float* __restrict__ mu, const int* __restrict__ tok_ids,
                         const float* __restrict__ rw, int H, int N,
                         int* __restrict__ eids) {
    int lane = threadIdx.x & 63;
    int wv   = threadIdx.x >> 6;
    int tok  = blockIdx.x * 4 + wv;
    if (tok >= N) return;
    float acc[8];
#pragma unroll
    for (int e = 0; e < 8; ++e) acc[e] = 0.f;
    const float* m = mu + (size_t)tok * H;
    for (int h = lane; h < H; h += 64) {
        float mv = m[h];
#pragma unroll
        for (int e = 0; e < 8; ++e) acc[e] += mv * rw[e * H + h];
    }
#pragma unroll
    for (int e = 0; e < 8; ++e) {
        float v = acc[e];
#pragma unroll
        for (int off = 32; off > 0; off >>= 1) v += __shfl_xor(v, off);
        acc[e] = v;
    }
    if (lane == 0) {
        int t = tok_ids[tok];
        if (t < 0) t = 0;
        if (t > VOCAB_SZ - 1) t = VOCAB_SZ - 1;
        int be = t % 8;
        float best = -1e30f; int bi = 0;
#pragma unroll
        for (int e = 0; e < 8; ++e) {
            float v = acc[e] + (e == be ? ROUTE_BIAS_F : 0.f);
            if (v > best) { best = v; bi = e; }
        }
        eids[tok] = bi;
    }
}

// ---------- router phase B: single-wave list build via ballot (no atomics) ----------
__global__ void k_build_list(const int* __restrict__ eids,
                             int* __restrict__ counts, int* __restrict__ base_,
                             int* __restrict__ list, int N) {
    int lane = threadIdx.x;   // 64 lanes, 1 wave
    unsigned long long below = (lane == 63) ? ~0ull >> 1
                             : ((1ull << lane) - 1ull);
    int cnt[8];
#pragma unroll
    for (int e = 0; e < 8; ++e) cnt[e] = 0;
    for (int i0 = 0; i0 < N; i0 += 64) {
        int tok = i0 + lane;
        int eid = eids[tok];
#pragma unroll
        for (int e = 0; e < 8; ++e) {
            unsigned long long m = __ballot(eid == e);
            if (eid == e)
                list[e * N + cnt[e] + __popcll(m & below)] = tok;
            cnt[e] += __popcll(m);
        }
    }
    if (lane == 0) {
        int s = 0;
#pragma unroll
        for (int e = 0; e < 8; ++e) {
            counts[e] = cnt[e];
            base_[e] = s;
            s += cnt[e];
        }
    }
}

// ---------- GEMM tile constants ----------
#define TM 128
#define TN 128
#define TK 64
#define LDSP 72   // padded LDS row length (bf16 elems)

// GEMM1: GU[compact_row][F2] = gather(X)[token][H] @ Wt[e][F2][H]^T
__global__ __launch_bounds__(256, 2) void k_gemm_gateup(
    const unsigned short* __restrict__ X,    // [N][H] bf16
    const unsigned short* __restrict__ Wt,   // [E][F2][H] bf16
    unsigned short* __restrict__ GU,         // [N][F2] bf16 compact rows
    const int* __restrict__ counts, const int* __restrict__ base_,
    const int* __restrict__ list, int N, int H, int F2) {
    int e = blockIdx.z, mt = blockIdx.y, nt = blockIdx.x;
    int cnt = counts[e];
    int m0 = mt * TM;
    if (m0 >= cnt) return;
    int n0 = nt * TN;

    __shared__ __align__(16) unsigned short As[TM * LDSP];
    __shared__ __align__(16) unsigned short Bs[TN * LDSP];

    int tid = threadIdx.x;
    int lane = tid & 63, wid = tid >> 6;
    int wm = (wid >> 1) * 64, wn = (wid & 1) * 64;

    f32x4 acc[4][4];
#pragma unroll
    for (int i = 0; i < 4; ++i)
#pragma unroll
        for (int j = 0; j < 4; ++j) acc[i][j] = (f32x4)(0.f);

    const unsigned short* We = Wt + ((size_t)e * F2 + n0) * H;

    const unsigned short* aptr[4];
#pragma unroll
    for (int i = 0; i < 4; ++i) {
        int chunk = tid + 256 * i;
        int r = chunk >> 3;
        int gr = m0 + r;
        aptr[i] = (gr < cnt) ? X + (size_t)list[e * N + gr] * H : nullptr;
    }

    for (int k0 = 0; k0 < H; k0 += TK) {
#pragma unroll
        for (int i = 0; i < 4; ++i) {
            int chunk = tid + 256 * i;
            int r = chunk >> 3, cc = (chunk & 7) * 8;
            uint4 v = make_uint4(0u, 0u, 0u, 0u);
            if (aptr[i]) v = *(const uint4*)(aptr[i] + k0 + cc);
            *(uint4*)&As[r * LDSP + cc] = v;
        }
#pragma unroll
        for (int i = 0; i < 4; ++i) {
            int chunk = tid + 256 * i;
            int r = chunk >> 3, cc = (chunk & 7) * 8;
            uint4 v = *(const uint4*)(We + (size_t)r * H + k0 + cc);
            *(uint4*)&Bs[r * LDSP + cc] = v;
        }
        __syncthreads();
#pragma unroll
        for (int ks = 0; ks < TK; ks += 32) {
            bf16x8 af[4], bfr[4];
            int kk = ks + (lane >> 4) * 8;
            int rA = wm + (lane & 15);
            int rB = wn + (lane & 15);
#pragma unroll
            for (int im = 0; im < 4; ++im)
                af[im] = *(const bf16x8*)&As[(rA + im * 16) * LDSP + kk];
#pragma unroll
            for (int in_ = 0; in_ < 4; ++in_)
                bfr[in_] = *(const bf16x8*)&Bs[(rB + in_ * 16) * LDSP + kk];
#pragma unroll
            for (int im = 0; im < 4; ++im)
#pragma unroll
                for (int in_ = 0; in_ < 4; ++in_)
                    acc[im][in_] = __builtin_amdgcn_mfma_f32_16x16x32_bf16(
                        af[im], bfr[in_], acc[im][in_], 0, 0, 0);
        }
        __syncthreads();
    }

    int b = base_[e];
#pragma unroll
    for (int im = 0; im < 4; ++im) {
#pragma unroll
        for (int j = 0; j < 4; ++j) {
            int row = wm + im * 16 + (lane >> 4) * 4 + j;
            int gr = m0 + row;
            if (gr < cnt) {
                unsigned short* orow = GU + (size_t)(b + gr) * F2 + n0;
#pragma unroll
                for (int in_ = 0; in_ < 4; ++in_) {
                    int col = wn + in_ * 16 + (lane & 15);
                    orow[col] = f2bf(acc[im][in_][j]);
                }
            }
        }
    }
}

// ---------- silu(gate)*up over compact rows ----------
__global__ void k_silu(const unsigned short* __restrict__ GU,
                       unsigned short* __restrict__ IT, int N, int Ie) {
    int idx = blockIdx.x * blockDim.x + threadIdx.x;
    if (idx >= N * Ie) return;
    int r = idx / Ie, c = idx - r * Ie;
    float g = bf2f(GU[(size_t)r * 2 * Ie + c]);
    float u = bf2f(GU[(size_t)r * 2 * Ie + Ie + c]);
    float s = g / (1.f + __expf(-g));
    IT[idx] = f2bf(s * u);
}

// GEMM2: OUT[token][H] = IT[compact_row][Ie] @ Wt[e][H][Ie]^T, rows scattered by list
__global__ __launch_bounds__(256, 2) void k_gemm_down(
    const unsigned short* __restrict__ IT,   // [N][Ie] bf16 compact
    const unsigned short* __restrict__ Wt,   // [E][H][Ie] bf16
    float* __restrict__ OUT,                 // [N][H] fp32 token-order
    const int* __restrict__ counts, const int* __restrict__ base_,
    const int* __restrict__ list, int N, int Ie, int H) {
    int e = blockIdx.z, mt = blockIdx.y, nt = blockIdx.x;
    int cnt = counts[e];
    int m0 = mt * TM;
    if (m0 >= cnt) return;
    int n0 = nt * TN;
    int b = base_[e];

    __shared__ __align__(16) unsigned short As[TM * LDSP];
    __shared__ __align__(16) unsigned short Bs[TN * LDSP];

    int tid = threadIdx.x;
    int lane = tid & 63, wid = tid >> 6;
    int wm = (wid >> 1) * 64, wn = (wid & 1) * 64;

    f32x4 acc[4][4];
#pragma unroll
    for (int i = 0; i < 4; ++i)
#pragma unroll
        for (int j = 0; j < 4; ++j) acc[i][j] = (f32x4)(0.f);

    const unsigned short* We = Wt + ((size_t)e * H + n0) * Ie;

    const unsigned short* aptr[4];
#pragma unroll
    for (int i = 0; i < 4; ++i) {
        int chunk = tid + 256 * i;
        int r = chunk >> 3;
        int gr = m0 + r;
        aptr[i] = (gr < cnt) ? IT + (size_t)(b + gr) * Ie : nullptr;
    }

    for (int k0 = 0; k0 < Ie; k0 += TK) {
#pragma unroll
        for (int i = 0; i < 4; ++i) {
            int chunk = tid + 256 * i;
            int r = chunk >> 3, cc = (chunk & 7) * 8;
            uint4 v = make_uint4(0u, 0u, 0u, 0u);
            if (aptr[i]) v = *(const uint4*)(aptr[i] + k0 + cc);
            *(uint4*)&As[r * LDSP + cc] = v;
        }
#pragma unroll
        for (int i = 0; i < 4; ++i) {
            int chunk = tid + 256 * i;
            int r = chunk >> 3, cc = (chunk & 7) * 8;
            uint4 v = *(const uint4*)(We + (size_t)r * Ie + k0 + cc);
            *(uint4*)&Bs[r * LDSP + cc] = v;
        }
        __syncthreads();
#pragma unroll
        for (int ks = 0; ks < TK; ks += 32) {
            bf16x8 af[4], bfr[4];
            int kk = ks + (lane >> 4) * 8;
            int rA = wm + (lane & 15);
            int rB = wn + (lane & 15);
#pragma unroll
            for (int im = 0; im < 4; ++im)
                af[im] = *(const bf16x8*)&As[(rA + im * 16) * LDSP + kk];
#pragma unroll
            for (int in_ = 0; in_ < 4; ++in_)
                bfr[in_] = *(const bf16x8*)&Bs[(rB + in_ * 16) * LDSP + kk];
#pragma unroll
            for (int im = 0; im < 4; ++im)
#pragma unroll
                for (int in_ = 0; in_ < 4; ++in_)
                    acc[im][in_] = __builtin_amdgcn_mfma_f32_16x16x32_bf16(
                        af[im], bfr[in_], acc[im][in_], 0, 0, 0);
        }
        __syncthreads();
    }

#pragma unroll
    for (int im = 0; im < 4; ++im) {
#pragma unroll
        for (int j = 0; j < 4; ++j) {
            int row = wm + im * 16 + (lane >> 4) * 4 + j;
            int gr = m0 + row;
            if (gr < cnt) {
                int tok = list[e * N + gr];
                float* orow = OUT + (size_t)tok * H + n0;
#pragma unroll
                for (int in_ = 0; in_ < 4; ++in_) {
                    int col = wn + in_ * 16 + (lane & 15);
                    orow[col] = acc[im][in_][j];
                }
            }
        }
    }
}

extern "C" void kernel_launch(void* const* d_in, const int* in_sizes, int n_in,
                              void* d_out, int out_size, void* d_ws, size_t ws_size,
                              hipStream_t stream) {
    const float* hidden   = (const float*)d_in[0];
    const int*   tok_ids  = (const int*)d_in[1];
    const float* mu       = (const float*)d_in[2];
    const float* gup      = (const float*)d_in[3];
    const float* dnp      = (const float*)d_in[4];
    const float* rw       = (const float*)d_in[5];
    float* out = (float*)d_out;

    int N  = in_sizes[1];                 // 8192
    int H  = in_sizes[0] / N;             // 1024
    int E  = in_sizes[5] / H;             // 8
    int F2 = in_sizes[3] / (E * H);       // 1024
    int Ie = F2 / 2;                      // 512

    char* ws = (char*)d_ws;
    size_t o = 0;
    auto alloc = [&](size_t sz) {
        size_t r = o;
        o += (sz + 255) & ~(size_t)255;
        return r;
    };
    int* counts = (int*)(ws + alloc((size_t)E * 4));
    int* base_  = (int*)(ws + alloc((size_t)E * 4));
    int* eids   = (int*)(ws + alloc((size_t)N * 4));
    int* list   = (int*)(ws + alloc((size_t)E * N * 4));
    unsigned short* xb   = (unsigned short*)(ws + alloc((size_t)N * H * 2));
    unsigned short* wgut = (unsigned short*)(ws + alloc((size_t)E * F2 * H * 2));
    unsigned short* wdnt = (unsigned short*)(ws + alloc((size_t)E * H * Ie * 2));
    unsigned short* gu   = (unsigned short*)(ws + alloc((size_t)N * F2 * 2));
    unsigned short* inter = xb;   // alias: xb dead after GEMM1

    k_convert_bf16<<<dim3((N * H / 4 + 255) / 256), dim3(256), 0, stream>>>(hidden, xb, N * H);

    dim3 tb(32, 8);
    k_transpose_bf16<<<dim3(F2 / 32, H / 32, E), tb, 0, stream>>>(gup, wgut, H, F2);
    k_transpose_bf16<<<dim3(H / 32, Ie / 32, E), tb, 0, stream>>>(dnp, wdnt, Ie, H);

    k_logits<<<dim3((N + 3) / 4), dim3(256), 0, stream>>>(mu, tok_ids, rw, H, N, eids);
    k_build_list<<<dim3(1), dim3(64), 0, stream>>>(eids, counts, base_, list, N);

    dim3 g1(F2 / TN, (N + TM - 1) / TM, E);
    k_gemm_gateup<<<g1, dim3(256), 0, stream>>>(xb, wgut, gu, counts, base_, list, N, H, F2);

    k_silu<<<dim3((N * Ie + 255) / 256), dim3(256), 0, stream>>>(gu, inter, N, Ie);

    dim3 g2(H / TN, (N + TM - 1) / TM, E);
    k_gemm_down<<<g2, dim3(256), 0, stream>>>(inter, wdnt, out, counts, base_, list, N, Ie, H);
}

// Round 3
// 266.601 us; speedup vs baseline: 1.3040x; 1.2433x over previous
//
#include <hip/hip_runtime.h>
#include <hip/hip_bf16.h>
#include <stdint.h>

typedef __bf16 bf16x8 __attribute__((ext_vector_type(8)));
typedef float f32x4 __attribute__((ext_vector_type(4)));

#define ROUTE_BIAS_F 10.0f
#define VOCAB_SZ 32000

// ---------- helpers ----------
__device__ __forceinline__ unsigned short f2bf(float f) {
    union { float f; unsigned u; } v; v.f = f;
    unsigned u = v.u;
    unsigned r = u + 0x7FFFu + ((u >> 16) & 1u);   // RNE
    return (unsigned short)(r >> 16);
}
__device__ __forceinline__ float bf2f(unsigned short s) {
    union { unsigned u; float f; } v; v.u = ((unsigned)s) << 16;
    return v.f;
}

// ---------- fp32 -> bf16 elementwise convert ----------
__global__ void k_convert_bf16(const float* __restrict__ in,
                               unsigned short* __restrict__ out, int n) {
    int i = (blockIdx.x * blockDim.x + threadIdx.x) * 4;
    if (i + 3 < n) {
        float4 f = *(const float4*)(in + i);
        ushort4 o;
        o.x = f2bf(f.x); o.y = f2bf(f.y); o.z = f2bf(f.z); o.w = f2bf(f.w);
        *(ushort4*)(out + i) = o;
    } else {
        for (; i < n; ++i) out[i] = f2bf(in[i]);
    }
}

// ---------- per-expert transpose + convert: in[R][C] fp32 -> out[C][R] bf16 ----------
__global__ void k_transpose_bf16(const float* __restrict__ in,
                                 unsigned short* __restrict__ out, int R, int C) {
    __shared__ float tile[32][33];
    int e = blockIdx.z;
    const float* inp = in + (size_t)e * R * C;
    unsigned short* outp = out + (size_t)e * R * C;
    int c0 = blockIdx.x * 32, r0 = blockIdx.y * 32;
    int tx = threadIdx.x, ty = threadIdx.y;   // 32 x 8
#pragma unroll
    for (int k = 0; k < 32; k += 8)
        tile[ty + k][tx] = inp[(size_t)(r0 + ty + k) * C + c0 + tx];
    __syncthreads();
#pragma unroll
    for (int k = 0; k < 32; k += 8)
        outp[(size_t)(c0 + ty + k) * R + r0 + tx] = f2bf(tile[tx][ty + k]);
}

// ---------- router phase A: fp32 logits + biased argmax, NO atomics ----------
__global__ void k_logits(const float* __restrict__ mu, const int* __restrict__ tok_ids,
                         const float* __restrict__ rw, int H, int N,
                         int* __restrict__ eids) {
    int lane = threadIdx.x & 63;
    int wv   = threadIdx.x >> 6;
    int tok  = blockIdx.x * 4 + wv;
    if (tok >= N) return;
    float acc[8];
#pragma unroll
    for (int e = 0; e < 8; ++e) acc[e] = 0.f;
    const float* m = mu + (size_t)tok * H;
    for (int h = lane; h < H; h += 64) {
        float mv = m[h];
#pragma unroll
        for (int e = 0; e < 8; ++e) acc[e] += mv * rw[e * H + h];
    }
#pragma unroll
    for (int e = 0; e < 8; ++e) {
        float v = acc[e];
#pragma unroll
        for (int off = 32; off > 0; off >>= 1) v += __shfl_xor(v, off);
        acc[e] = v;
    }
    if (lane == 0) {
        int t = tok_ids[tok];
        if (t < 0) t = 0;
        if (t > VOCAB_SZ - 1) t = VOCAB_SZ - 1;
        int be = t % 8;
        float best = -1e30f; int bi = 0;
#pragma unroll
        for (int e = 0; e < 8; ++e) {
            float v = acc[e] + (e == be ? ROUTE_BIAS_F : 0.f);
            if (v > best) { best = v; bi = e; }
        }
        eids[tok] = bi;
    }
}

// ---------- router phase B: parallel counting sort (no global atomics) ----------
// B1: per-block expert counts. 256 thr/block, 1 token/thread.
__global__ void k_count(const int* __restrict__ eids,
                        int* __restrict__ blockcnt, int N) {
    __shared__ int cnt[8];
    int tid = threadIdx.x;
    if (tid < 8) cnt[tid] = 0;
    __syncthreads();
    int tok = blockIdx.x * 256 + tid;
    int lane = tid & 63;
    int eid = (tok < N) ? eids[tok] : -1;
#pragma unroll
    for (int e = 0; e < 8; ++e) {
        unsigned long long m = __ballot(eid == e);
        if (lane == 0 && m) atomicAdd(&cnt[e], __popcll(m));
    }
    __syncthreads();
    if (tid < 8) blockcnt[blockIdx.x * 8 + tid] = cnt[tid];
}

// B2: prefix over blocks per expert (8 threads, 32 iterations each).
__global__ void k_scan(const int* __restrict__ blockcnt,
                       int* __restrict__ counts, int* __restrict__ base_,
                       int* __restrict__ offs, int NB) {
    __shared__ int scnt[8];
    int e = threadIdx.x;
    if (e < 8) {
        int s = 0;
        for (int b = 0; b < NB; ++b) {
            offs[b * 8 + e] = s;
            s += blockcnt[b * 8 + e];
        }
        scnt[e] = s;
        counts[e] = s;
    }
    __syncthreads();
    if (e == 0) {
        int s = 0;
#pragma unroll
        for (int i = 0; i < 8; ++i) { base_[i] = s; s += scnt[i]; }
    }
}

// B3: scatter tokens into per-expert lists using ballot ranks.
__global__ void k_scatter(const int* __restrict__ eids,
                          const int* __restrict__ offs,
                          int* __restrict__ list, int N) {
    __shared__ int wavecnt[4][8];
    int tid = threadIdx.x;
    int lane = tid & 63, wv = tid >> 6;
    int tok = blockIdx.x * 256 + tid;
    int eid = (tok < N) ? eids[tok] : -1;
    unsigned long long below = (1ull << lane) - 1ull;
    int myrank = 0;
#pragma unroll
    for (int e = 0; e < 8; ++e) {
        unsigned long long m = __ballot(eid == e);
        if (lane == 0) wavecnt[wv][e] = __popcll(m);
        if (eid == e) myrank = __popcll(m & below);
    }
    __syncthreads();
    if (eid >= 0) {
        int pre = 0;
        for (int w = 0; w < wv; ++w) pre += wavecnt[w][eid];
        int pos = offs[blockIdx.x * 8 + eid] + pre + myrank;
        list[eid * N + pos] = tok;
    }
}

// ---------- GEMM tile constants ----------
#define TM 128
#define TN 128
#define TK 64
#define LDSP 72   // padded LDS row length (bf16 elems)

// GEMM1: GU[compact_row][F2] = gather(X)[token][H] @ Wt[e][F2][H]^T
__global__ __launch_bounds__(256, 2) void k_gemm_gateup(
    const unsigned short* __restrict__ X,    // [N][H] bf16
    const unsigned short* __restrict__ Wt,   // [E][F2][H] bf16
    unsigned short* __restrict__ GU,         // [N][F2] bf16 compact rows
    const int* __restrict__ counts, const int* __restrict__ base_,
    const int* __restrict__ list, int N, int H, int F2) {
    int e = blockIdx.z, mt = blockIdx.y, nt = blockIdx.x;
    int cnt = counts[e];
    int m0 = mt * TM;
    if (m0 >= cnt) return;
    int n0 = nt * TN;

    __shared__ __align__(16) unsigned short As[TM * LDSP];
    __shared__ __align__(16) unsigned short Bs[TN * LDSP];

    int tid = threadIdx.x;
    int lane = tid & 63, wid = tid >> 6;
    int wm = (wid >> 1) * 64, wn = (wid & 1) * 64;

    f32x4 acc[4][4];
#pragma unroll
    for (int i = 0; i < 4; ++i)
#pragma unroll
        for (int j = 0; j < 4; ++j) acc[i][j] = (f32x4)(0.f);

    const unsigned short* We = Wt + ((size_t)e * F2 + n0) * H;

    const unsigned short* aptr[4];
#pragma unroll
    for (int i = 0; i < 4; ++i) {
        int chunk = tid + 256 * i;
        int r = chunk >> 3;
        int gr = m0 + r;
        aptr[i] = (gr < cnt) ? X + (size_t)list[e * N + gr] * H : nullptr;
    }

    for (int k0 = 0; k0 < H; k0 += TK) {
#pragma unroll
        for (int i = 0; i < 4; ++i) {
            int chunk = tid + 256 * i;
            int r = chunk >> 3, cc = (chunk & 7) * 8;
            uint4 v = make_uint4(0u, 0u, 0u, 0u);
            if (aptr[i]) v = *(const uint4*)(aptr[i] + k0 + cc);
            *(uint4*)&As[r * LDSP + cc] = v;
        }
#pragma unroll
        for (int i = 0; i < 4; ++i) {
            int chunk = tid + 256 * i;
            int r = chunk >> 3, cc = (chunk & 7) * 8;
            uint4 v = *(const uint4*)(We + (size_t)r * H + k0 + cc);
            *(uint4*)&Bs[r * LDSP + cc] = v;
        }
        __syncthreads();
#pragma unroll
        for (int ks = 0; ks < TK; ks += 32) {
            bf16x8 af[4], bfr[4];
            int kk = ks + (lane >> 4) * 8;
            int rA = wm + (lane & 15);
            int rB = wn + (lane & 15);
#pragma unroll
            for (int im = 0; im < 4; ++im)
                af[im] = *(const bf16x8*)&As[(rA + im * 16) * LDSP + kk];
#pragma unroll
            for (int in_ = 0; in_ < 4; ++in_)
                bfr[in_] = *(const bf16x8*)&Bs[(rB + in_ * 16) * LDSP + kk];
#pragma unroll
            for (int im = 0; im < 4; ++im)
#pragma unroll
                for (int in_ = 0; in_ < 4; ++in_)
                    acc[im][in_] = __builtin_amdgcn_mfma_f32_16x16x32_bf16(
                        af[im], bfr[in_], acc[im][in_], 0, 0, 0);
        }
        __syncthreads();
    }

    int b = base_[e];
#pragma unroll
    for (int im = 0; im < 4; ++im) {
#pragma unroll
        for (int j = 0; j < 4; ++j) {
            int row = wm + im * 16 + (lane >> 4) * 4 + j;
            int gr = m0 + row;
            if (gr < cnt) {
                unsigned short* orow = GU + (size_t)(b + gr) * F2 + n0;
#pragma unroll
                for (int in_ = 0; in_ < 4; ++in_) {
                    int col = wn + in_ * 16 + (lane & 15);
                    orow[col] = f2bf(acc[im][in_][j]);
                }
            }
        }
    }
}

// ---------- silu(gate)*up over compact rows ----------
__global__ void k_silu(const unsigned short* __restrict__ GU,
                       unsigned short* __restrict__ IT, int N, int Ie) {
    int idx = blockIdx.x * blockDim.x + threadIdx.x;
    if (idx >= N * Ie) return;
    int r = idx / Ie, c = idx - r * Ie;
    float g = bf2f(GU[(size_t)r * 2 * Ie + c]);
    float u = bf2f(GU[(size_t)r * 2 * Ie + Ie + c]);
    float s = g / (1.f + __expf(-g));
    IT[idx] = f2bf(s * u);
}

// GEMM2: OUT[token][H] = IT[compact_row][Ie] @ Wt[e][H][Ie]^T, rows scattered by list
__global__ __launch_bounds__(256, 2) void k_gemm_down(
    const unsigned short* __restrict__ IT,   // [N][Ie] bf16 compact
    const unsigned short* __restrict__ Wt,   // [E][H][Ie] bf16
    float* __restrict__ OUT,                 // [N][H] fp32 token-order
    const int* __restrict__ counts, const int* __restrict__ base_,
    const int* __restrict__ list, int N, int Ie, int H) {
    int e = blockIdx.z, mt = blockIdx.y, nt = blockIdx.x;
    int cnt = counts[e];
    int m0 = mt * TM;
    if (m0 >= cnt) return;
    int n0 = nt * TN;
    int b = base_[e];

    __shared__ __align__(16) unsigned short As[TM * LDSP];
    __shared__ __align__(16) unsigned short Bs[TN * LDSP];

    int tid = threadIdx.x;
    int lane = tid & 63, wid = tid >> 6;
    int wm = (wid >> 1) * 64, wn = (wid & 1) * 64;

    f32x4 acc[4][4];
#pragma unroll
    for (int i = 0; i < 4; ++i)
#pragma unroll
        for (int j = 0; j < 4; ++j) acc[i][j] = (f32x4)(0.f);

    const unsigned short* We = Wt + ((size_t)e * H + n0) * Ie;

    const unsigned short* aptr[4];
#pragma unroll
    for (int i = 0; i < 4; ++i) {
        int chunk = tid + 256 * i;
        int r = chunk >> 3;
        int gr = m0 + r;
        aptr[i] = (gr < cnt) ? IT + (size_t)(b + gr) * Ie : nullptr;
    }

    for (int k0 = 0; k0 < Ie; k0 += TK) {
#pragma unroll
        for (int i = 0; i < 4; ++i) {
            int chunk = tid + 256 * i;
            int r = chunk >> 3, cc = (chunk & 7) * 8;
            uint4 v = make_uint4(0u, 0u, 0u, 0u);
            if (aptr[i]) v = *(const uint4*)(aptr[i] + k0 + cc);
            *(uint4*)&As[r * LDSP + cc] = v;
        }
#pragma unroll
        for (int i = 0; i < 4; ++i) {
            int chunk = tid + 256 * i;
            int r = chunk >> 3, cc = (chunk & 7) * 8;
            uint4 v = *(const uint4*)(We + (size_t)r * Ie + k0 + cc);
            *(uint4*)&Bs[r * LDSP + cc] = v;
        }
        __syncthreads();
#pragma unroll
        for (int ks = 0; ks < TK; ks += 32) {
            bf16x8 af[4], bfr[4];
            int kk = ks + (lane >> 4) * 8;
            int rA = wm + (lane & 15);
            int rB = wn + (lane & 15);
#pragma unroll
            for (int im = 0; im < 4; ++im)
                af[im] = *(const bf16x8*)&As[(rA + im * 16) * LDSP + kk];
#pragma unroll
            for (int in_ = 0; in_ < 4; ++in_)
                bfr[in_] = *(const bf16x8*)&Bs[(rB + in_ * 16) * LDSP + kk];
#pragma unroll
            for (int im = 0; im < 4; ++im)
#pragma unroll
                for (int in_ = 0; in_ < 4; ++in_)
                    acc[im][in_] = __builtin_amdgcn_mfma_f32_16x16x32_bf16(
                        af[im], bfr[in_], acc[im][in_], 0, 0, 0);
        }
        __syncthreads();
    }

#pragma unroll
    for (int im = 0; im < 4; ++im) {
#pragma unroll
        for (int j = 0; j < 4; ++j) {
            int row = wm + im * 16 + (lane >> 4) * 4 + j;
            int gr = m0 + row;
            if (gr < cnt) {
                int tok = list[e * N + gr];
                float* orow = OUT + (size_t)tok * H + n0;
#pragma unroll
                for (int in_ = 0; in_ < 4; ++in_) {
                    int col = wn + in_ * 16 + (lane & 15);
                    orow[col] = acc[im][in_][j];
                }
            }
        }
    }
}

extern "C" void kernel_launch(void* const* d_in, const int* in_sizes, int n_in,
                              void* d_out, int out_size, void* d_ws, size_t ws_size,
                              hipStream_t stream) {
    const float* hidden   = (const float*)d_in[0];
    const int*   tok_ids  = (const int*)d_in[1];
    const float* mu       = (const float*)d_in[2];
    const float* gup      = (const float*)d_in[3];
    const float* dnp      = (const float*)d_in[4];
    const float* rw       = (const float*)d_in[5];
    float* out = (float*)d_out;

    int N  = in_sizes[1];                 // 8192
    int H  = in_sizes[0] / N;             // 1024
    int E  = in_sizes[5] / H;             // 8
    int F2 = in_sizes[3] / (E * H);       // 1024
    int Ie = F2 / 2;                      // 512

    int NB = (N + 255) / 256;             // 32

    char* ws = (char*)d_ws;
    size_t o = 0;
    auto alloc = [&](size_t sz) {
        size_t r = o;
        o += (sz + 255) & ~(size_t)255;
        return r;
    };
    int* counts   = (int*)(ws + alloc((size_t)E * 4));
    int* base_    = (int*)(ws + alloc((size_t)E * 4));
    int* eids     = (int*)(ws + alloc((size_t)N * 4));
    int* blockcnt = (int*)(ws + alloc((size_t)NB * 8 * 4));
    int* offs     = (int*)(ws + alloc((size_t)NB * 8 * 4));
    int* list     = (int*)(ws + alloc((size_t)E * N * 4));
    unsigned short* xb   = (unsigned short*)(ws + alloc((size_t)N * H * 2));
    unsigned short* wgut = (unsigned short*)(ws + alloc((size_t)E * F2 * H * 2));
    unsigned short* wdnt = (unsigned short*)(ws + alloc((size_t)E * H * Ie * 2));
    unsigned short* gu   = (unsigned short*)(ws + alloc((size_t)N * F2 * 2));
    unsigned short* inter = xb;   // alias: xb dead after GEMM1

    k_convert_bf16<<<dim3((N * H / 4 + 255) / 256), dim3(256), 0, stream>>>(hidden, xb, N * H);

    dim3 tb(32, 8);
    k_transpose_bf16<<<dim3(F2 / 32, H / 32, E), tb, 0, stream>>>(gup, wgut, H, F2);
    k_transpose_bf16<<<dim3(H / 32, Ie / 32, E), tb, 0, stream>>>(dnp, wdnt, Ie, H);

    k_logits<<<dim3((N + 3) / 4), dim3(256), 0, stream>>>(mu, tok_ids, rw, H, N, eids);
    k_count<<<dim3(NB), dim3(256), 0, stream>>>(eids, blockcnt, N);
    k_scan<<<dim3(1), dim3(64), 0, stream>>>(blockcnt, counts, base_, offs, NB);
    k_scatter<<<dim3(NB), dim3(256), 0, stream>>>(eids, offs, list, N);

    dim3 g1(F2 / TN, (N + TM - 1) / TM, E);
    k_gemm_gateup<<<g1, dim3(256), 0, stream>>>(xb, wgut, gu, counts, base_, list, N, H, F2);

    k_silu<<<dim3((N * Ie + 255) / 256), dim3(256), 0, stream>>>(gu, inter, N, Ie);

    dim3 g2(H / TN, (N + TM - 1) / TM, E);
    k_gemm_down<<<g2, dim3(256), 0, stream>>>(inter, wdnt, out, counts, base_, list, N, Ie, H);
}

// Round 4
// 245.090 us; speedup vs baseline: 1.4184x; 1.0878x over previous
//
#include <hip/hip_runtime.h>
#include <hip/hip_bf16.h>
#include <stdint.h>

typedef __bf16 bf16x8 __attribute__((ext_vector_type(8)));
typedef float f32x4 __attribute__((ext_vector_type(4)));

#define ROUTE_BIAS_F 10.0f
#define VOCAB_SZ 32000

// ---------- helpers ----------
__device__ __forceinline__ unsigned short f2bf(float f) {
    union { float f; unsigned u; } v; v.f = f;
    unsigned u = v.u;
    unsigned r = u + 0x7FFFu + ((u >> 16) & 1u);   // RNE
    return (unsigned short)(r >> 16);
}
__device__ __forceinline__ float bf2f(unsigned short s) {
    union { unsigned u; float f; } v; v.u = ((unsigned)s) << 16;
    return v.f;
}
// async 16B global->LDS copy (lds dest must be wave-uniform; HW adds lane*16)
__device__ __forceinline__ void ld16(const unsigned short* g, unsigned short* l) {
    __builtin_amdgcn_global_load_lds(
        (const __attribute__((address_space(1))) void*)g,
        (__attribute__((address_space(3))) void*)l, 16, 0, 0);
}

// ---------- fp32 -> bf16 elementwise convert ----------
__global__ void k_convert_bf16(const float* __restrict__ in,
                               unsigned short* __restrict__ out, int n) {
    int i = (blockIdx.x * blockDim.x + threadIdx.x) * 4;
    if (i + 3 < n) {
        float4 f = *(const float4*)(in + i);
        ushort4 o;
        o.x = f2bf(f.x); o.y = f2bf(f.y); o.z = f2bf(f.z); o.w = f2bf(f.w);
        *(ushort4*)(out + i) = o;
    } else {
        for (; i < n; ++i) out[i] = f2bf(in[i]);
    }
}

// ---------- per-expert transpose + convert: in[R][C] fp32 -> out[C][R] bf16 ----------
__global__ void k_transpose_bf16(const float* __restrict__ in,
                                 unsigned short* __restrict__ out, int R, int C) {
    __shared__ float tile[32][33];
    int e = blockIdx.z;
    const float* inp = in + (size_t)e * R * C;
    unsigned short* outp = out + (size_t)e * R * C;
    int c0 = blockIdx.x * 32, r0 = blockIdx.y * 32;
    int tx = threadIdx.x, ty = threadIdx.y;   // 32 x 8
#pragma unroll
    for (int k = 0; k < 32; k += 8)
        tile[ty + k][tx] = inp[(size_t)(r0 + ty + k) * C + c0 + tx];
    __syncthreads();
#pragma unroll
    for (int k = 0; k < 32; k += 8)
        outp[(size_t)(c0 + ty + k) * R + r0 + tx] = f2bf(tile[tx][ty + k]);
}

// ---------- router phase A: fp32 logits + biased argmax, NO atomics ----------
__global__ void k_logits(const float* __restrict__ mu, const int* __restrict__ tok_ids,
                         const float* __restrict__ rw, int H, int N,
                         int* __restrict__ eids) {
    int lane = threadIdx.x & 63;
    int wv   = threadIdx.x >> 6;
    int tok  = blockIdx.x * 4 + wv;
    if (tok >= N) return;
    float acc[8];
#pragma unroll
    for (int e = 0; e < 8; ++e) acc[e] = 0.f;
    const float* m = mu + (size_t)tok * H;
    for (int h = lane; h < H; h += 64) {
        float mv = m[h];
#pragma unroll
        for (int e = 0; e < 8; ++e) acc[e] += mv * rw[e * H + h];
    }
#pragma unroll
    for (int e = 0; e < 8; ++e) {
        float v = acc[e];
#pragma unroll
        for (int off = 32; off > 0; off >>= 1) v += __shfl_xor(v, off);
        acc[e] = v;
    }
    if (lane == 0) {
        int t = tok_ids[tok];
        if (t < 0) t = 0;
        if (t > VOCAB_SZ - 1) t = VOCAB_SZ - 1;
        int be = t % 8;
        float best = -1e30f; int bi = 0;
#pragma unroll
        for (int e = 0; e < 8; ++e) {
            float v = acc[e] + (e == be ? ROUTE_BIAS_F : 0.f);
            if (v > best) { best = v; bi = e; }
        }
        eids[tok] = bi;
    }
}

// ---------- router phase B: parallel counting sort (no global atomics) ----------
__global__ void k_count(const int* __restrict__ eids,
                        int* __restrict__ blockcnt, int N) {
    __shared__ int cnt[8];
    int tid = threadIdx.x;
    if (tid < 8) cnt[tid] = 0;
    __syncthreads();
    int tok = blockIdx.x * 256 + tid;
    int lane = tid & 63;
    int eid = (tok < N) ? eids[tok] : -1;
#pragma unroll
    for (int e = 0; e < 8; ++e) {
        unsigned long long m = __ballot(eid == e);
        if (lane == 0 && m) atomicAdd(&cnt[e], __popcll(m));
    }
    __syncthreads();
    if (tid < 8) blockcnt[blockIdx.x * 8 + tid] = cnt[tid];
}

// B2: one wave. lane = e*8+g; group g scans 4 blocks; shuffle-scan across groups.
__global__ void k_scan(const int* __restrict__ blockcnt,
                       int* __restrict__ counts, int* __restrict__ base_,
                       int* __restrict__ offs, int NB) {   // NB == 32
    __shared__ int tot[8];
    int lane = threadIdx.x;       // 64
    int e = lane >> 3, g = lane & 7;
    int v[4];
    int s = 0;
#pragma unroll
    for (int i = 0; i < 4; ++i) { v[i] = s; s += blockcnt[(g * 4 + i) * 8 + e]; }
    int inc = s;
#pragma unroll
    for (int d = 1; d < 8; d <<= 1) {
        int t = __shfl_up(inc, d);
        if (g >= d) inc += t;
    }
    int excl = inc - s;
#pragma unroll
    for (int i = 0; i < 4; ++i) offs[(g * 4 + i) * 8 + e] = excl + v[i];
    if (g == 7) { counts[e] = inc; tot[e] = inc; }
    __syncthreads();
    if (lane == 0) {
        int s2 = 0;
#pragma unroll
        for (int i = 0; i < 8; ++i) { base_[i] = s2; s2 += tot[i]; }
    }
}

// B3: scatter tokens into per-expert lists using ballot ranks.
__global__ void k_scatter(const int* __restrict__ eids,
                          const int* __restrict__ offs,
                          int* __restrict__ list, int N) {
    __shared__ int wavecnt[4][8];
    int tid = threadIdx.x;
    int lane = tid & 63, wv = tid >> 6;
    int tok = blockIdx.x * 256 + tid;
    int eid = (tok < N) ? eids[tok] : -1;
    unsigned long long below = (1ull << lane) - 1ull;
    int myrank = 0;
#pragma unroll
    for (int e = 0; e < 8; ++e) {
        unsigned long long m = __ballot(eid == e);
        if (lane == 0) wavecnt[wv][e] = __popcll(m);
        if (eid == e) myrank = __popcll(m & below);
    }
    __syncthreads();
    if (eid >= 0) {
        int pre = 0;
        for (int w = 0; w < wv; ++w) pre += wavecnt[w][eid];
        int pos = offs[blockIdx.x * 8 + eid] + pre + myrank;
        list[eid * N + pos] = tok;
    }
}

// ---------- GEMM tile constants ----------
#define TM 128
#define TN 128
#define TK 64
// LDS row = TK bf16 = 128B = 8 chunks of 16B, unpadded (global_load_lds needs
// linear lane*16 placement). Bank conflicts avoided by XOR chunk swizzle
// applied on the GLOBAL address side: slot s of row r holds global chunk s^(r&7).

// GEMM1: GU[compact_row][F2] = gather(X)[token][H] @ Wt[e][F2][H]^T
__global__ __launch_bounds__(256, 2) void k_gemm_gateup(
    const unsigned short* __restrict__ X,    // [N][H] bf16
    const unsigned short* __restrict__ Wt,   // [E][F2][H] bf16
    unsigned short* __restrict__ GU,         // [N][F2] bf16 compact rows
    const int* __restrict__ counts, const int* __restrict__ base_,
    const int* __restrict__ list, int N, int H, int F2) {
    int e = blockIdx.z, mt = blockIdx.y, nt = blockIdx.x;
    int cnt = counts[e];
    int m0 = mt * TM;
    if (m0 >= cnt) return;
    int n0 = nt * TN;

    __shared__ __align__(16) unsigned short As[TM * TK];
    __shared__ __align__(16) unsigned short Bs[TN * TK];

    int tid = threadIdx.x;
    int lane = tid & 63, wv = tid >> 6;
    int wm = (wv >> 1) * 64, wn = (wv & 1) * 64;

    int rowg = lane >> 3;            // 0..7 row within 8-row group
    int sl   = (lane & 7) ^ rowg;    // swizzled source chunk for staging

    const unsigned short* We = Wt + ((size_t)e * F2 + n0) * H;
    const unsigned short* ag[4];
    const unsigned short* bg[4];
#pragma unroll
    for (int i = 0; i < 4; ++i) {
        int r = wv * 32 + i * 8 + rowg;          // tile row 0..127
        int gr = m0 + r;
        int tokrow = (gr < cnt) ? list[e * N + gr] : 0;
        ag[i] = X + (size_t)tokrow * H + sl * 8;
        bg[i] = We + (size_t)r * H + sl * 8;
    }

    f32x4 acc[4][4];
#pragma unroll
    for (int i = 0; i < 4; ++i)
#pragma unroll
        for (int j = 0; j < 4; ++j) acc[i][j] = (f32x4)(0.f);

    int q = lane >> 4, m = lane & 15;
    int sw = m & 7;                  // row-dependent chunk swizzle for frag reads

    for (int k0 = 0; k0 < H; k0 += TK) {
#pragma unroll
        for (int i = 0; i < 4; ++i)
            ld16(ag[i] + k0, &As[(wv * 32 + i * 8) * TK]);
#pragma unroll
        for (int i = 0; i < 4; ++i)
            ld16(bg[i] + k0, &Bs[(wv * 32 + i * 8) * TK]);
        __syncthreads();
#pragma unroll
        for (int ks = 0; ks < TK; ks += 32) {
            int kc = ks >> 3;        // base chunk: 0 or 4
            int ck = ((kc + q) ^ sw) << 3;
            bf16x8 af[4], bfr[4];
#pragma unroll
            for (int im = 0; im < 4; ++im)
                af[im] = *(const bf16x8*)&As[(wm + m + im * 16) * TK + ck];
#pragma unroll
            for (int in_ = 0; in_ < 4; ++in_)
                bfr[in_] = *(const bf16x8*)&Bs[(wn + m + in_ * 16) * TK + ck];
#pragma unroll
            for (int im = 0; im < 4; ++im)
#pragma unroll
                for (int in_ = 0; in_ < 4; ++in_)
                    acc[im][in_] = __builtin_amdgcn_mfma_f32_16x16x32_bf16(
                        af[im], bfr[in_], acc[im][in_], 0, 0, 0);
        }
        __syncthreads();
    }

    int b = base_[e];
#pragma unroll
    for (int im = 0; im < 4; ++im) {
#pragma unroll
        for (int j = 0; j < 4; ++j) {
            int row = wm + im * 16 + (lane >> 4) * 4 + j;
            int gr = m0 + row;
            if (gr < cnt) {
                unsigned short* orow = GU + (size_t)(b + gr) * F2 + n0;
#pragma unroll
                for (int in_ = 0; in_ < 4; ++in_) {
                    int col = wn + in_ * 16 + (lane & 15);
                    orow[col] = f2bf(acc[im][in_][j]);
                }
            }
        }
    }
}

// ---------- silu(gate)*up over compact rows, 8 elems/thread ----------
__global__ void k_silu(const unsigned short* __restrict__ GU,
                       unsigned short* __restrict__ IT, int N, int Ie) {
    int idx = blockIdx.x * blockDim.x + threadIdx.x;   // one 8-elem chunk
    int total = (N * Ie) >> 3;
    if (idx >= total) return;
    int per_row = Ie >> 3;
    int r = idx / per_row, c = (idx - r * per_row) * 8;
    const unsigned short* g8 = GU + (size_t)r * 2 * Ie + c;
    const unsigned short* u8 = g8 + Ie;
    ushort4 ga = *(const ushort4*)g8, gb = *(const ushort4*)(g8 + 4);
    ushort4 ua = *(const ushort4*)u8, ub = *(const ushort4*)(u8 + 4);
    unsigned short o[8];
    unsigned short gs[8] = {ga.x, ga.y, ga.z, ga.w, gb.x, gb.y, gb.z, gb.w};
    unsigned short us[8] = {ua.x, ua.y, ua.z, ua.w, ub.x, ub.y, ub.z, ub.w};
#pragma unroll
    for (int i = 0; i < 8; ++i) {
        float g = bf2f(gs[i]), u = bf2f(us[i]);
        float s = g / (1.f + __expf(-g));
        o[i] = f2bf(s * u);
    }
    ushort4 oa = {o[0], o[1], o[2], o[3]}, ob = {o[4], o[5], o[6], o[7]};
    unsigned short* op = IT + (size_t)r * Ie + c;
    *(ushort4*)op = oa;
    *(ushort4*)(op + 4) = ob;
}

// GEMM2: OUT[token][H] = IT[compact_row][Ie] @ Wt[e][H][Ie]^T, rows scattered by list
__global__ __launch_bounds__(256, 2) void k_gemm_down(
    const unsigned short* __restrict__ IT,   // [N][Ie] bf16 compact
    const unsigned short* __restrict__ Wt,   // [E][H][Ie] bf16
    float* __restrict__ OUT,                 // [N][H] fp32 token-order
    const int* __restrict__ counts, const int* __restrict__ base_,
    const int* __restrict__ list, int N, int Ie, int H) {
    int e = blockIdx.z, mt = blockIdx.y, nt = blockIdx.x;
    int cnt = counts[e];
    int m0 = mt * TM;
    if (m0 >= cnt) return;
    int n0 = nt * TN;
    int b = base_[e];

    __shared__ __align__(16) unsigned short As[TM * TK];
    __shared__ __align__(16) unsigned short Bs[TN * TK];

    int tid = threadIdx.x;
    int lane = tid & 63, wv = tid >> 6;
    int wm = (wv >> 1) * 64, wn = (wv & 1) * 64;

    int rowg = lane >> 3;
    int sl   = (lane & 7) ^ rowg;

    const unsigned short* We = Wt + ((size_t)e * H + n0) * Ie;
    const unsigned short* ag[4];
    const unsigned short* bg[4];
#pragma unroll
    for (int i = 0; i < 4; ++i) {
        int r = wv * 32 + i * 8 + rowg;
        int gr = m0 + r;
        int arow = (gr < cnt) ? (b + gr) : b;
        ag[i] = IT + (size_t)arow * Ie + sl * 8;
        bg[i] = We + (size_t)r * Ie + sl * 8;
    }

    f32x4 acc[4][4];
#pragma unroll
    for (int i = 0; i < 4; ++i)
#pragma unroll
        for (int j = 0; j < 4; ++j) acc[i][j] = (f32x4)(0.f);

    int q = lane >> 4, m = lane & 15;
    int sw = m & 7;

    for (int k0 = 0; k0 < Ie; k0 += TK) {
#pragma unroll
        for (int i = 0; i < 4; ++i)
            ld16(ag[i] + k0, &As[(wv * 32 + i * 8) * TK]);
#pragma unroll
        for (int i = 0; i < 4; ++i)
            ld16(bg[i] + k0, &Bs[(wv * 32 + i * 8) * TK]);
        __syncthreads();
#pragma unroll
        for (int ks = 0; ks < TK; ks += 32) {
            int kc = ks >> 3;
            int ck = ((kc + q) ^ sw) << 3;
            bf16x8 af[4], bfr[4];
#pragma unroll
            for (int im = 0; im < 4; ++im)
                af[im] = *(const bf16x8*)&As[(wm + m + im * 16) * TK + ck];
#pragma unroll
            for (int in_ = 0; in_ < 4; ++in_)
                bfr[in_] = *(const bf16x8*)&Bs[(wn + m + in_ * 16) * TK + ck];
#pragma unroll
            for (int im = 0; im < 4; ++im)
#pragma unroll
                for (int in_ = 0; in_ < 4; ++in_)
                    acc[im][in_] = __builtin_amdgcn_mfma_f32_16x16x32_bf16(
                        af[im], bfr[in_], acc[im][in_], 0, 0, 0);
        }
        __syncthreads();
    }

#pragma unroll
    for (int im = 0; im < 4; ++im) {
#pragma unroll
        for (int j = 0; j < 4; ++j) {
            int row = wm + im * 16 + (lane >> 4) * 4 + j;
            int gr = m0 + row;
            if (gr < cnt) {
                int tok = list[e * N + gr];
                float* orow = OUT + (size_t)tok * H + n0;
#pragma unroll
                for (int in_ = 0; in_ < 4; ++in_) {
                    int col = wn + in_ * 16 + (lane & 15);
                    orow[col] = acc[im][in_][j];
                }
            }
        }
    }
}

extern "C" void kernel_launch(void* const* d_in, const int* in_sizes, int n_in,
                              void* d_out, int out_size, void* d_ws, size_t ws_size,
                              hipStream_t stream) {
    const float* hidden   = (const float*)d_in[0];
    const int*   tok_ids  = (const int*)d_in[1];
    const float* mu       = (const float*)d_in[2];
    const float* gup      = (const float*)d_in[3];
    const float* dnp      = (const float*)d_in[4];
    const float* rw       = (const float*)d_in[5];
    float* out = (float*)d_out;

    int N  = in_sizes[1];                 // 8192
    int H  = in_sizes[0] / N;             // 1024
    int E  = in_sizes[5] / H;             // 8
    int F2 = in_sizes[3] / (E * H);       // 1024
    int Ie = F2 / 2;                      // 512

    int NB = (N + 255) / 256;             // 32

    char* ws = (char*)d_ws;
    size_t o = 0;
    auto alloc = [&](size_t sz) {
        size_t r = o;
        o += (sz + 255) & ~(size_t)255;
        return r;
    };
    int* counts   = (int*)(ws + alloc((size_t)E * 4));
    int* base_    = (int*)(ws + alloc((size_t)E * 4));
    int* eids     = (int*)(ws + alloc((size_t)N * 4));
    int* blockcnt = (int*)(ws + alloc((size_t)NB * 8 * 4));
    int* offs     = (int*)(ws + alloc((size_t)NB * 8 * 4));
    int* list     = (int*)(ws + alloc((size_t)E * N * 4));
    unsigned short* xb   = (unsigned short*)(ws + alloc((size_t)N * H * 2));
    unsigned short* wgut = (unsigned short*)(ws + alloc((size_t)E * F2 * H * 2));
    unsigned short* wdnt = (unsigned short*)(ws + alloc((size_t)E * H * Ie * 2));
    unsigned short* gu   = (unsigned short*)(ws + alloc((size_t)N * F2 * 2));
    unsigned short* inter = xb;   // alias: xb dead after GEMM1

    k_convert_bf16<<<dim3((N * H / 4 + 255) / 256), dim3(256), 0, stream>>>(hidden, xb, N * H);

    dim3 tb(32, 8);
    k_transpose_bf16<<<dim3(F2 / 32, H / 32, E), tb, 0, stream>>>(gup, wgut, H, F2);
    k_transpose_bf16<<<dim3(H / 32, Ie / 32, E), tb, 0, stream>>>(dnp, wdnt, Ie, H);

    k_logits<<<dim3((N + 3) / 4), dim3(256), 0, stream>>>(mu, tok_ids, rw, H, N, eids);
    k_count<<<dim3(NB), dim3(256), 0, stream>>>(eids, blockcnt, N);
    k_scan<<<dim3(1), dim3(64), 0, stream>>>(blockcnt, counts, base_, offs, NB);
    k_scatter<<<dim3(NB), dim3(256), 0, stream>>>(eids, offs, list, N);

    dim3 g1(F2 / TN, (N + TM - 1) / TM, E);
    k_gemm_gateup<<<g1, dim3(256), 0, stream>>>(xb, wgut, gu, counts, base_, list, N, H, F2);

    k_silu<<<dim3((N * Ie / 8 + 255) / 256), dim3(256), 0, stream>>>(gu, inter, N, Ie);

    dim3 g2(H / TN, (N + TM - 1) / TM, E);
    k_gemm_down<<<g2, dim3(256), 0, stream>>>(inter, wdnt, out, counts, base_, list, N, Ie, H);
}

// Round 5
// 240.045 us; speedup vs baseline: 1.4482x; 1.0210x over previous
//
#include <hip/hip_runtime.h>
#include <hip/hip_bf16.h>
#include <stdint.h>

typedef __bf16 bf16x8 __attribute__((ext_vector_type(8)));
typedef float f32x4 __attribute__((ext_vector_type(4)));

#define ROUTE_BIAS_F 10.0f
#define VOCAB_SZ 32000

// ---------- helpers ----------
__device__ __forceinline__ unsigned short f2bf(float f) {
    union { float f; unsigned u; } v; v.f = f;
    unsigned u = v.u;
    unsigned r = u + 0x7FFFu + ((u >> 16) & 1u);   // RNE
    return (unsigned short)(r >> 16);
}
__device__ __forceinline__ float bf2f(unsigned short s) {
    union { unsigned u; float f; } v; v.u = ((unsigned)s) << 16;
    return v.f;
}
// async 16B global->LDS copy (lds dest wave-uniform; HW adds lane*16)
__device__ __forceinline__ void ld16(const unsigned short* g, unsigned short* l) {
    __builtin_amdgcn_global_load_lds(
        (const __attribute__((address_space(1))) void*)g,
        (__attribute__((address_space(3))) void*)l, 16, 0, 0);
}

// ---------- fp32 -> bf16 elementwise convert ----------
__global__ void k_convert_bf16(const float* __restrict__ in,
                               unsigned short* __restrict__ out, int n) {
    int i = (blockIdx.x * blockDim.x + threadIdx.x) * 4;
    if (i + 3 < n) {
        float4 f = *(const float4*)(in + i);
        ushort4 o;
        o.x = f2bf(f.x); o.y = f2bf(f.y); o.z = f2bf(f.z); o.w = f2bf(f.w);
        *(ushort4*)(out + i) = o;
    } else {
        for (; i < n; ++i) out[i] = f2bf(in[i]);
    }
}

// ---------- per-expert transpose + convert: in[R][C] fp32 -> out[C][R] bf16 ----------
__global__ void k_transpose_bf16(const float* __restrict__ in,
                                 unsigned short* __restrict__ out, int R, int C) {
    __shared__ float tile[32][33];
    int e = blockIdx.z;
    const float* inp = in + (size_t)e * R * C;
    unsigned short* outp = out + (size_t)e * R * C;
    int c0 = blockIdx.x * 32, r0 = blockIdx.y * 32;
    int tx = threadIdx.x, ty = threadIdx.y;   // 32 x 8
#pragma unroll
    for (int k = 0; k < 32; k += 8)
        tile[ty + k][tx] = inp[(size_t)(r0 + ty + k) * C + c0 + tx];
    __syncthreads();
#pragma unroll
    for (int k = 0; k < 32; k += 8)
        outp[(size_t)(c0 + ty + k) * R + r0 + tx] = f2bf(tile[tx][ty + k]);
}

// ---------- router phase A: fp32 logits + biased argmax ----------
__global__ void k_logits(const float* __restrict__ mu, const int* __restrict__ tok_ids,
                         const float* __restrict__ rw, int H, int N,
                         int* __restrict__ eids) {
    int lane = threadIdx.x & 63;
    int wv   = threadIdx.x >> 6;
    int tok  = blockIdx.x * 4 + wv;
    if (tok >= N) return;
    float acc[8];
#pragma unroll
    for (int e = 0; e < 8; ++e) acc[e] = 0.f;
    const float* m = mu + (size_t)tok * H;
    for (int h = lane; h < H; h += 64) {
        float mv = m[h];
#pragma unroll
        for (int e = 0; e < 8; ++e) acc[e] += mv * rw[e * H + h];
    }
#pragma unroll
    for (int e = 0; e < 8; ++e) {
        float v = acc[e];
#pragma unroll
        for (int off = 32; off > 0; off >>= 1) v += __shfl_xor(v, off);
        acc[e] = v;
    }
    if (lane == 0) {
        int t = tok_ids[tok];
        if (t < 0) t = 0;
        if (t > VOCAB_SZ - 1) t = VOCAB_SZ - 1;
        int be = t % 8;
        float best = -1e30f; int bi = 0;
#pragma unroll
        for (int e = 0; e < 8; ++e) {
            float v = acc[e] + (e == be ? ROUTE_BIAS_F : 0.f);
            if (v > best) { best = v; bi = e; }
        }
        eids[tok] = bi;
    }
}

// ---------- router phase B: parallel counting sort ----------
__global__ void k_count(const int* __restrict__ eids,
                        int* __restrict__ blockcnt, int N) {
    __shared__ int cnt[8];
    int tid = threadIdx.x;
    if (tid < 8) cnt[tid] = 0;
    __syncthreads();
    int tok = blockIdx.x * 256 + tid;
    int lane = tid & 63;
    int eid = (tok < N) ? eids[tok] : -1;
#pragma unroll
    for (int e = 0; e < 8; ++e) {
        unsigned long long m = __ballot(eid == e);
        if (lane == 0 && m) atomicAdd(&cnt[e], __popcll(m));
    }
    __syncthreads();
    if (tid < 8) blockcnt[blockIdx.x * 8 + tid] = cnt[tid];
}

// B2: one wave; lane = e*8+g; group g scans 4 blocks; shuffle-scan across groups.
__global__ void k_scan(const int* __restrict__ blockcnt,
                       int* __restrict__ counts, int* __restrict__ base_,
                       int* __restrict__ offs, int NB) {   // NB == 32
    __shared__ int tot[8];
    int lane = threadIdx.x;
    int e = lane >> 3, g = lane & 7;
    int v[4];
    int s = 0;
#pragma unroll
    for (int i = 0; i < 4; ++i) { v[i] = s; s += blockcnt[(g * 4 + i) * 8 + e]; }
    int inc = s;
#pragma unroll
    for (int d = 1; d < 8; d <<= 1) {
        int t = __shfl_up(inc, d);
        if (g >= d) inc += t;
    }
    int excl = inc - s;
#pragma unroll
    for (int i = 0; i < 4; ++i) offs[(g * 4 + i) * 8 + e] = excl + v[i];
    if (g == 7) { counts[e] = inc; tot[e] = inc; }
    __syncthreads();
    if (lane == 0) {
        int s2 = 0;
#pragma unroll
        for (int i = 0; i < 8; ++i) { base_[i] = s2; s2 += tot[i]; }
    }
}

// B3: scatter tokens into per-expert lists using ballot ranks.
__global__ void k_scatter(const int* __restrict__ eids,
                          const int* __restrict__ offs,
                          int* __restrict__ list, int N) {
    __shared__ int wavecnt[4][8];
    int tid = threadIdx.x;
    int lane = tid & 63, wv = tid >> 6;
    int tok = blockIdx.x * 256 + tid;
    int eid = (tok < N) ? eids[tok] : -1;
    unsigned long long below = (1ull << lane) - 1ull;
    int myrank = 0;
#pragma unroll
    for (int e = 0; e < 8; ++e) {
        unsigned long long m = __ballot(eid == e);
        if (lane == 0) wavecnt[wv][e] = __popcll(m);
        if (eid == e) myrank = __popcll(m & below);
    }
    __syncthreads();
    if (eid >= 0) {
        int pre = 0;
        for (int w = 0; w < wv; ++w) pre += wavecnt[w][eid];
        int pos = offs[blockIdx.x * 8 + eid] + pre + myrank;
        list[eid * N + pos] = tok;
    }
}

// ---------- GEMM tile constants ----------
#define TM 128
#define TN 128
#define TK 64
// LDS row = 64 bf16 = 128B = 8x16B chunks, unpadded. XOR chunk swizzle on the
// GLOBAL address side: slot s of row r holds global chunk s^(r&7) -> 2-way max
// bank aliasing on frag reads (free per m136). Double-buffered: prefetch tile
// k+1 issued right after the barrier, before computing tile k -> ~1 compute
// phase of flight before the next barrier's vmcnt(0) drain.

// GEMM1 fused: IT[compact_row][Ie] = silu(gate)*up of gather(X) @ Wgu^T.
// B-tile rows interleave gate/up: tile col 2c = gate col (nt*64+c), 2c+1 = up.
__global__ __launch_bounds__(256, 2) void k_gemm_gateup(
    const unsigned short* __restrict__ X,    // [N][H] bf16
    const unsigned short* __restrict__ Wt,   // [E][F2][H] bf16 (f-major)
    unsigned short* __restrict__ IT,         // [N][Ie] bf16 compact rows
    const int* __restrict__ counts, const int* __restrict__ base_,
    const int* __restrict__ list, int N, int H, int Ie) {
    int bid = blockIdx.x;
    int e = bid & 7;                 // XCD-pinned expert
    int t = bid >> 3;
    int nt = t & 7;                  // 8 n-tiles of 64 out cols
    int mt = t >> 3;
    int cnt = counts[e];
    int m0 = mt * TM;
    if (m0 >= cnt) return;
    int F2 = 2 * Ie;

    __shared__ __align__(16) unsigned short As[2][TM * TK];
    __shared__ __align__(16) unsigned short Bs[2][TN * TK];

    int tid = threadIdx.x;
    int lane = tid & 63, wv = tid >> 6;
    int wm = (wv >> 1) * 64, wn = (wv & 1) * 64;

    int rowg = lane >> 3;            // 0..7 row within 8-row group
    int sl   = (lane & 7) ^ rowg;    // swizzled source chunk for staging

    const unsigned short* ag[4];
    const unsigned short* bg[4];
#pragma unroll
    for (int i = 0; i < 4; ++i) {
        int r = wv * 32 + i * 8 + rowg;          // tile row 0..127
        int gr = m0 + r;
        int tokrow = (gr < cnt) ? list[e * N + gr] : 0;
        ag[i] = X + (size_t)tokrow * H + sl * 8;
        // interleaved gate/up weight row
        int wrow = (r & 1) * Ie + nt * 64 + (r >> 1);
        bg[i] = Wt + ((size_t)e * F2 + wrow) * H + sl * 8;
    }

    f32x4 acc[4][4];
#pragma unroll
    for (int i = 0; i < 4; ++i)
#pragma unroll
        for (int j = 0; j < 4; ++j) acc[i][j] = (f32x4)(0.f);

    int q = lane >> 4, m = lane & 15;
    int sw = m & 7;

    // prologue: tile 0 -> buf 0
#pragma unroll
    for (int i = 0; i < 4; ++i) ld16(ag[i], &As[0][(wv * 32 + i * 8) * TK]);
#pragma unroll
    for (int i = 0; i < 4; ++i) ld16(bg[i], &Bs[0][(wv * 32 + i * 8) * TK]);

    int NKI = H / TK;
    int p = 0;
    for (int ki = 0; ki < NKI; ++ki, p ^= 1) {
        __syncthreads();             // drains own prefetch, publishes buf p
        if (ki + 1 < NKI) {
            int kn = (ki + 1) * TK;
#pragma unroll
            for (int i = 0; i < 4; ++i) ld16(ag[i] + kn, &As[p ^ 1][(wv * 32 + i * 8) * TK]);
#pragma unroll
            for (int i = 0; i < 4; ++i) ld16(bg[i] + kn, &Bs[p ^ 1][(wv * 32 + i * 8) * TK]);
        }
#pragma unroll
        for (int ks = 0; ks < TK; ks += 32) {
            int kc = ks >> 3;
            int ck = ((kc + q) ^ sw) << 3;
            bf16x8 af[4], bfr[4];
#pragma unroll
            for (int im = 0; im < 4; ++im)
                af[im] = *(const bf16x8*)&As[p][(wm + m + im * 16) * TK + ck];
#pragma unroll
            for (int in_ = 0; in_ < 4; ++in_)
                bfr[in_] = *(const bf16x8*)&Bs[p][(wn + m + in_ * 16) * TK + ck];
#pragma unroll
            for (int im = 0; im < 4; ++im)
#pragma unroll
                for (int in_ = 0; in_ < 4; ++in_)
                    acc[im][in_] = __builtin_amdgcn_mfma_f32_16x16x32_bf16(
                        af[im], bfr[in_], acc[im][in_], 0, 0, 0);
        }
    }

    // epilogue: pair even(gate)/odd(up) lanes, silu in fp32, write IT
    int b = base_[e];
    int nt64 = nt * 64;
#pragma unroll
    for (int im = 0; im < 4; ++im) {
#pragma unroll
        for (int j = 0; j < 4; ++j) {
            int row = wm + im * 16 + q * 4 + j;
            int gr = m0 + row;
#pragma unroll
            for (int in_ = 0; in_ < 4; ++in_) {
                float v = acc[im][in_][j];
                float u = __shfl_xor(v, 1);
                float g = v;
                float s = g / (1.f + __expf(-g));
                float res = s * u;
                if (!(lane & 1) && gr < cnt) {
                    int oc = nt64 + ((wn + in_ * 16 + m) >> 1);
                    IT[(size_t)(b + gr) * Ie + oc] = f2bf(res);
                }
            }
        }
    }
}

// GEMM2: OUT[token][H] = IT[compact_row][Ie] @ Wd^T, rows scattered by list
__global__ __launch_bounds__(256, 2) void k_gemm_down(
    const unsigned short* __restrict__ IT,   // [N][Ie] bf16 compact
    const unsigned short* __restrict__ Wt,   // [E][H][Ie] bf16 (h-major)
    float* __restrict__ OUT,                 // [N][H] fp32 token-order
    const int* __restrict__ counts, const int* __restrict__ base_,
    const int* __restrict__ list, int N, int Ie, int H) {
    int bid = blockIdx.x;
    int e = bid & 7;                 // XCD-pinned expert
    int t = bid >> 3;
    int nt = t & 7;                  // H/TN = 8
    int mt = t >> 3;
    int cnt = counts[e];
    int m0 = mt * TM;
    if (m0 >= cnt) return;
    int n0 = nt * TN;
    int b = base_[e];

    __shared__ __align__(16) unsigned short As[2][TM * TK];
    __shared__ __align__(16) unsigned short Bs[2][TN * TK];

    int tid = threadIdx.x;
    int lane = tid & 63, wv = tid >> 6;
    int wm = (wv >> 1) * 64, wn = (wv & 1) * 64;

    int rowg = lane >> 3;
    int sl   = (lane & 7) ^ rowg;

    const unsigned short* We = Wt + ((size_t)e * H + n0) * Ie;
    const unsigned short* ag[4];
    const unsigned short* bg[4];
#pragma unroll
    for (int i = 0; i < 4; ++i) {
        int r = wv * 32 + i * 8 + rowg;
        int gr = m0 + r;
        int arow = (gr < cnt) ? (b + gr) : b;
        ag[i] = IT + (size_t)arow * Ie + sl * 8;
        bg[i] = We + (size_t)r * Ie + sl * 8;
    }

    f32x4 acc[4][4];
#pragma unroll
    for (int i = 0; i < 4; ++i)
#pragma unroll
        for (int j = 0; j < 4; ++j) acc[i][j] = (f32x4)(0.f);

    int q = lane >> 4, m = lane & 15;
    int sw = m & 7;

#pragma unroll
    for (int i = 0; i < 4; ++i) ld16(ag[i], &As[0][(wv * 32 + i * 8) * TK]);
#pragma unroll
    for (int i = 0; i < 4; ++i) ld16(bg[i], &Bs[0][(wv * 32 + i * 8) * TK]);

    int NKI = Ie / TK;
    int p = 0;
    for (int ki = 0; ki < NKI; ++ki, p ^= 1) {
        __syncthreads();
        if (ki + 1 < NKI) {
            int kn = (ki + 1) * TK;
#pragma unroll
            for (int i = 0; i < 4; ++i) ld16(ag[i] + kn, &As[p ^ 1][(wv * 32 + i * 8) * TK]);
#pragma unroll
            for (int i = 0; i < 4; ++i) ld16(bg[i] + kn, &Bs[p ^ 1][(wv * 32 + i * 8) * TK]);
        }
#pragma unroll
        for (int ks = 0; ks < TK; ks += 32) {
            int kc = ks >> 3;
            int ck = ((kc + q) ^ sw) << 3;
            bf16x8 af[4], bfr[4];
#pragma unroll
            for (int im = 0; im < 4; ++im)
                af[im] = *(const bf16x8*)&As[p][(wm + m + im * 16) * TK + ck];
#pragma unroll
            for (int in_ = 0; in_ < 4; ++in_)
                bfr[in_] = *(const bf16x8*)&Bs[p][(wn + m + in_ * 16) * TK + ck];
#pragma unroll
            for (int im = 0; im < 4; ++im)
#pragma unroll
                for (int in_ = 0; in_ < 4; ++in_)
                    acc[im][in_] = __builtin_amdgcn_mfma_f32_16x16x32_bf16(
                        af[im], bfr[in_], acc[im][in_], 0, 0, 0);
        }
    }

#pragma unroll
    for (int im = 0; im < 4; ++im) {
#pragma unroll
        for (int j = 0; j < 4; ++j) {
            int row = wm + im * 16 + q * 4 + j;
            int gr = m0 + row;
            if (gr < cnt) {
                int tok = list[e * N + gr];
                float* orow = OUT + (size_t)tok * H + n0;
#pragma unroll
                for (int in_ = 0; in_ < 4; ++in_) {
                    int col = wn + in_ * 16 + m;
                    orow[col] = acc[im][in_][j];
                }
            }
        }
    }
}

extern "C" void kernel_launch(void* const* d_in, const int* in_sizes, int n_in,
                              void* d_out, int out_size, void* d_ws, size_t ws_size,
                              hipStream_t stream) {
    const float* hidden   = (const float*)d_in[0];
    const int*   tok_ids  = (const int*)d_in[1];
    const float* mu       = (const float*)d_in[2];
    const float* gup      = (const float*)d_in[3];
    const float* dnp      = (const float*)d_in[4];
    const float* rw       = (const float*)d_in[5];
    float* out = (float*)d_out;

    int N  = in_sizes[1];                 // 8192
    int H  = in_sizes[0] / N;             // 1024
    int E  = in_sizes[5] / H;             // 8
    int F2 = in_sizes[3] / (E * H);       // 1024
    int Ie = F2 / 2;                      // 512

    int NB = (N + 255) / 256;             // 32

    char* ws = (char*)d_ws;
    size_t o = 0;
    auto alloc = [&](size_t sz) {
        size_t r = o;
        o += (sz + 255) & ~(size_t)255;
        return r;
    };
    int* counts   = (int*)(ws + alloc((size_t)E * 4));
    int* base_    = (int*)(ws + alloc((size_t)E * 4));
    int* eids     = (int*)(ws + alloc((size_t)N * 4));
    int* blockcnt = (int*)(ws + alloc((size_t)NB * 8 * 4));
    int* offs     = (int*)(ws + alloc((size_t)NB * 8 * 4));
    int* list     = (int*)(ws + alloc((size_t)E * N * 4));
    unsigned short* xb   = (unsigned short*)(ws + alloc((size_t)N * H * 2));
    unsigned short* wgut = (unsigned short*)(ws + alloc((size_t)E * F2 * H * 2));
    unsigned short* wdnt = (unsigned short*)(ws + alloc((size_t)E * H * Ie * 2));
    unsigned short* it   = (unsigned short*)(ws + alloc((size_t)N * Ie * 2));

    k_convert_bf16<<<dim3((N * H / 4 + 255) / 256), dim3(256), 0, stream>>>(hidden, xb, N * H);

    dim3 tb(32, 8);
    k_transpose_bf16<<<dim3(F2 / 32, H / 32, E), tb, 0, stream>>>(gup, wgut, H, F2);
    k_transpose_bf16<<<dim3(H / 32, Ie / 32, E), tb, 0, stream>>>(dnp, wdnt, Ie, H);

    k_logits<<<dim3((N + 3) / 4), dim3(256), 0, stream>>>(mu, tok_ids, rw, H, N, eids);
    k_count<<<dim3(NB), dim3(256), 0, stream>>>(eids, blockcnt, N);
    k_scan<<<dim3(1), dim3(64), 0, stream>>>(blockcnt, counts, base_, offs, NB);
    k_scatter<<<dim3(NB), dim3(256), 0, stream>>>(eids, offs, list, N);

    int MT = (N + TM - 1) / TM;           // 64
    // flat XCD-pinned grids: bid&7 = expert
    k_gemm_gateup<<<dim3(E * MT * (Ie / 64)), dim3(256), 0, stream>>>(
        xb, wgut, it, counts, base_, list, N, H, Ie);

    k_gemm_down<<<dim3(E * MT * (H / TN)), dim3(256), 0, stream>>>(
        it, wdnt, out, counts, base_, list, N, Ie, H);
}

// Round 6
// 227.541 us; speedup vs baseline: 1.5278x; 1.0550x over previous
//
#include <hip/hip_runtime.h>
#include <hip/hip_bf16.h>
#include <stdint.h>

typedef __bf16 bf16x8 __attribute__((ext_vector_type(8)));
typedef float f32x4 __attribute__((ext_vector_type(4)));

#define ROUTE_BIAS_F 10.0f
#define VOCAB_SZ 32000

// ---------- helpers ----------
__device__ __forceinline__ unsigned short f2bf(float f) {
    union { float f; unsigned u; } v; v.f = f;
    unsigned u = v.u;
    unsigned r = u + 0x7FFFu + ((u >> 16) & 1u);   // RNE
    return (unsigned short)(r >> 16);
}
__device__ __forceinline__ float bf2f(unsigned short s) {
    union { unsigned u; float f; } v; v.u = ((unsigned)s) << 16;
    return v.f;
}
// async 16B global->LDS copy (lds dest wave-uniform; HW adds lane*16)
__device__ __forceinline__ void ld16(const unsigned short* g, unsigned short* l) {
    __builtin_amdgcn_global_load_lds(
        (const __attribute__((address_space(1))) void*)g,
        (__attribute__((address_space(3))) void*)l, 16, 0, 0);
}

// ---------- fp32 -> bf16 elementwise convert ----------
__global__ void k_convert_bf16(const float* __restrict__ in,
                               unsigned short* __restrict__ out, int n) {
    int i = (blockIdx.x * blockDim.x + threadIdx.x) * 4;
    if (i + 3 < n) {
        float4 f = *(const float4*)(in + i);
        ushort4 o;
        o.x = f2bf(f.x); o.y = f2bf(f.y); o.z = f2bf(f.z); o.w = f2bf(f.w);
        *(ushort4*)(out + i) = o;
    } else {
        for (; i < n; ++i) out[i] = f2bf(in[i]);
    }
}

// ---------- per-expert transpose + convert: in[R][C] fp32 -> out[C][R] bf16 ----------
__global__ void k_transpose_bf16(const float* __restrict__ in,
                                 unsigned short* __restrict__ out, int R, int C) {
    __shared__ float tile[32][33];
    int e = blockIdx.z;
    const float* inp = in + (size_t)e * R * C;
    unsigned short* outp = out + (size_t)e * R * C;
    int c0 = blockIdx.x * 32, r0 = blockIdx.y * 32;
    int tx = threadIdx.x, ty = threadIdx.y;   // 32 x 8
#pragma unroll
    for (int k = 0; k < 32; k += 8)
        tile[ty + k][tx] = inp[(size_t)(r0 + ty + k) * C + c0 + tx];
    __syncthreads();
#pragma unroll
    for (int k = 0; k < 32; k += 8)
        outp[(size_t)(c0 + ty + k) * R + r0 + tx] = f2bf(tile[tx][ty + k]);
}

// ---------- router phase A: fp32 logits + biased argmax ----------
__global__ void k_logits(const float* __restrict__ mu, const int* __restrict__ tok_ids,
                         const float* __restrict__ rw, int H, int N,
                         int* __restrict__ eids) {
    int lane = threadIdx.x & 63;
    int wv   = threadIdx.x >> 6;
    int tok  = blockIdx.x * 4 + wv;
    if (tok >= N) return;
    float acc[8];
#pragma unroll
    for (int e = 0; e < 8; ++e) acc[e] = 0.f;
    const float* m = mu + (size_t)tok * H;
    for (int h = lane; h < H; h += 64) {
        float mv = m[h];
#pragma unroll
        for (int e = 0; e < 8; ++e) acc[e] += mv * rw[e * H + h];
    }
#pragma unroll
    for (int e = 0; e < 8; ++e) {
        float v = acc[e];
#pragma unroll
        for (int off = 32; off > 0; off >>= 1) v += __shfl_xor(v, off);
        acc[e] = v;
    }
    if (lane == 0) {
        int t = tok_ids[tok];
        if (t < 0) t = 0;
        if (t > VOCAB_SZ - 1) t = VOCAB_SZ - 1;
        int be = t % 8;
        float best = -1e30f; int bi = 0;
#pragma unroll
        for (int e = 0; e < 8; ++e) {
            float v = acc[e] + (e == be ? ROUTE_BIAS_F : 0.f);
            if (v > best) { best = v; bi = e; }
        }
        eids[tok] = bi;
    }
}

// ---------- router phase B: parallel counting sort ----------
__global__ void k_count(const int* __restrict__ eids,
                        int* __restrict__ blockcnt, int N) {
    __shared__ int cnt[8];
    int tid = threadIdx.x;
    if (tid < 8) cnt[tid] = 0;
    __syncthreads();
    int tok = blockIdx.x * 256 + tid;
    int lane = tid & 63;
    int eid = (tok < N) ? eids[tok] : -1;
#pragma unroll
    for (int e = 0; e < 8; ++e) {
        unsigned long long m = __ballot(eid == e);
        if (lane == 0 && m) atomicAdd(&cnt[e], __popcll(m));
    }
    __syncthreads();
    if (tid < 8) blockcnt[blockIdx.x * 8 + tid] = cnt[tid];
}

// B2: one wave; lane = e*8+g; group g scans 4 blocks; shuffle-scan across groups.
__global__ void k_scan(const int* __restrict__ blockcnt,
                       int* __restrict__ counts, int* __restrict__ base_,
                       int* __restrict__ offs, int NB) {   // NB == 32
    __shared__ int tot[8];
    int lane = threadIdx.x;
    int e = lane >> 3, g = lane & 7;
    int v[4];
    int s = 0;
#pragma unroll
    for (int i = 0; i < 4; ++i) { v[i] = s; s += blockcnt[(g * 4 + i) * 8 + e]; }
    int inc = s;
#pragma unroll
    for (int d = 1; d < 8; d <<= 1) {
        int t = __shfl_up(inc, d);
        if (g >= d) inc += t;
    }
    int excl = inc - s;
#pragma unroll
    for (int i = 0; i < 4; ++i) offs[(g * 4 + i) * 8 + e] = excl + v[i];
    if (g == 7) { counts[e] = inc; tot[e] = inc; }
    __syncthreads();
    if (lane == 0) {
        int s2 = 0;
#pragma unroll
        for (int i = 0; i < 8; ++i) { base_[i] = s2; s2 += tot[i]; }
    }
}

// B3: scatter tokens into per-expert lists using ballot ranks.
__global__ void k_scatter(const int* __restrict__ eids,
                          const int* __restrict__ offs,
                          int* __restrict__ list, int N) {
    __shared__ int wavecnt[4][8];
    int tid = threadIdx.x;
    int lane = tid & 63, wv = tid >> 6;
    int tok = blockIdx.x * 256 + tid;
    int eid = (tok < N) ? eids[tok] : -1;
    unsigned long long below = (1ull << lane) - 1ull;
    int myrank = 0;
#pragma unroll
    for (int e = 0; e < 8; ++e) {
        unsigned long long m = __ballot(eid == e);
        if (lane == 0) wavecnt[wv][e] = __popcll(m);
        if (eid == e) myrank = __popcll(m & below);
    }
    __syncthreads();
    if (eid >= 0) {
        int pre = 0;
        for (int w = 0; w < wv; ++w) pre += wavecnt[w][eid];
        int pos = offs[blockIdx.x * 8 + eid] + pre + myrank;
        list[eid * N + pos] = tok;
    }
}

// ---------- GEMM tile constants ----------
#define TM 64
#define TN 128
#define TK 64
// LDS row = 64 bf16 = 128B = 8x16B chunks, unpadded. XOR chunk swizzle on the
// GLOBAL address side: slot s of row r holds global chunk s^(r&7) -> <=2-way
// bank aliasing on frag reads (free per m136). Single-buffered 2-barrier
// K-loop (m97 structure); occupancy 4 blocks/CU is the latency-hiding lever.

// GEMM1 fused: IT[compact_row][Ie] = silu(gate)*up of gather(X) @ Wgu^T.
// B-tile rows interleave gate/up: tile row 2c = gate col (nt*64+c), 2c+1 = up.
__global__ __launch_bounds__(256, 4) void k_gemm_gateup(
    const unsigned short* __restrict__ X,    // [N][H] bf16
    const unsigned short* __restrict__ Wt,   // [E][F2][H] bf16 (f-major)
    unsigned short* __restrict__ IT,         // [N][Ie] bf16 compact rows
    const int* __restrict__ counts, const int* __restrict__ base_,
    const int* __restrict__ list, int N, int H, int Ie) {
    int bid = blockIdx.x;
    int e = bid & 7;                 // XCD-pinned expert
    int t = bid >> 3;
    int nt = t & 7;                  // 8 n-tiles of 64 out cols (128 interleaved)
    int mt = t >> 3;                 // 0..127
    int cnt = counts[e];
    int m0 = mt * TM;
    if (m0 >= cnt) return;
    int F2 = 2 * Ie;

    __shared__ __align__(16) unsigned short As[TM * TK];   // 8 KB
    __shared__ __align__(16) unsigned short Bs[TN * TK];   // 16 KB

    int tid = threadIdx.x;
    int lane = tid & 63, wv = tid >> 6;
    int wm = (wv >> 1) * 32, wn = (wv & 1) * 64;   // wave tile 32x64

    int rowg = lane >> 3;            // 0..7 row within 8-row group
    int sl   = (lane & 7) ^ rowg;    // swizzled source chunk for staging

    const unsigned short* ag[2];
    const unsigned short* bg[4];
#pragma unroll
    for (int i = 0; i < 2; ++i) {
        int r = wv * 16 + i * 8 + rowg;          // A tile row 0..63
        int gr = m0 + r;
        int tokrow = (gr < cnt) ? list[e * N + gr] : 0;
        ag[i] = X + (size_t)tokrow * H + sl * 8;
    }
#pragma unroll
    for (int i = 0; i < 4; ++i) {
        int r = wv * 32 + i * 8 + rowg;          // B tile row 0..127
        int wrow = (r & 1) * Ie + nt * 64 + (r >> 1);
        bg[i] = Wt + ((size_t)e * F2 + wrow) * H + sl * 8;
    }

    f32x4 acc[2][4];
#pragma unroll
    for (int i = 0; i < 2; ++i)
#pragma unroll
        for (int j = 0; j < 4; ++j) acc[i][j] = (f32x4)(0.f);

    int q = lane >> 4, m = lane & 15;
    int sw = m & 7;

    for (int k0 = 0; k0 < H; k0 += TK) {
#pragma unroll
        for (int i = 0; i < 2; ++i)
            ld16(ag[i] + k0, &As[(wv * 16 + i * 8) * TK]);
#pragma unroll
        for (int i = 0; i < 4; ++i)
            ld16(bg[i] + k0, &Bs[(wv * 32 + i * 8) * TK]);
        __syncthreads();
#pragma unroll
        for (int ks = 0; ks < TK; ks += 32) {
            int kc = ks >> 3;
            int ck = ((kc + q) ^ sw) << 3;
            bf16x8 af[2], bfr[4];
#pragma unroll
            for (int im = 0; im < 2; ++im)
                af[im] = *(const bf16x8*)&As[(wm + m + im * 16) * TK + ck];
#pragma unroll
            for (int in_ = 0; in_ < 4; ++in_)
                bfr[in_] = *(const bf16x8*)&Bs[(wn + m + in_ * 16) * TK + ck];
#pragma unroll
            for (int im = 0; im < 2; ++im)
#pragma unroll
                for (int in_ = 0; in_ < 4; ++in_)
                    acc[im][in_] = __builtin_amdgcn_mfma_f32_16x16x32_bf16(
                        af[im], bfr[in_], acc[im][in_], 0, 0, 0);
        }
        __syncthreads();
    }

    // epilogue: pair even(gate)/odd(up) lanes, silu in fp32, write IT
    int b = base_[e];
    int nt64 = nt * 64;
#pragma unroll
    for (int im = 0; im < 2; ++im) {
#pragma unroll
        for (int j = 0; j < 4; ++j) {
            int row = wm + im * 16 + q * 4 + j;
            int gr = m0 + row;
#pragma unroll
            for (int in_ = 0; in_ < 4; ++in_) {
                float v = acc[im][in_][j];
                float u = __shfl_xor(v, 1);
                float g = v;
                float s = g / (1.f + __expf(-g));
                float res = s * u;
                if (!(lane & 1) && gr < cnt) {
                    int oc = nt64 + ((wn + in_ * 16 + m) >> 1);
                    IT[(size_t)(b + gr) * Ie + oc] = f2bf(res);
                }
            }
        }
    }
}

// GEMM2: OUT[token][H] = IT[compact_row][Ie] @ Wd^T, rows scattered by list
__global__ __launch_bounds__(256, 4) void k_gemm_down(
    const unsigned short* __restrict__ IT,   // [N][Ie] bf16 compact
    const unsigned short* __restrict__ Wt,   // [E][H][Ie] bf16 (h-major)
    float* __restrict__ OUT,                 // [N][H] fp32 token-order
    const int* __restrict__ counts, const int* __restrict__ base_,
    const int* __restrict__ list, int N, int Ie, int H) {
    int bid = blockIdx.x;
    int e = bid & 7;                 // XCD-pinned expert
    int t = bid >> 3;
    int nt = t & 7;                  // H/TN = 8
    int mt = t >> 3;                 // 0..127
    int cnt = counts[e];
    int m0 = mt * TM;
    if (m0 >= cnt) return;
    int n0 = nt * TN;
    int b = base_[e];

    __shared__ __align__(16) unsigned short As[TM * TK];
    __shared__ __align__(16) unsigned short Bs[TN * TK];

    int tid = threadIdx.x;
    int lane = tid & 63, wv = tid >> 6;
    int wm = (wv >> 1) * 32, wn = (wv & 1) * 64;

    int rowg = lane >> 3;
    int sl   = (lane & 7) ^ rowg;

    const unsigned short* We = Wt + ((size_t)e * H + n0) * Ie;
    const unsigned short* ag[2];
    const unsigned short* bg[4];
#pragma unroll
    for (int i = 0; i < 2; ++i) {
        int r = wv * 16 + i * 8 + rowg;
        int gr = m0 + r;
        int arow = (gr < cnt) ? (b + gr) : b;
        ag[i] = IT + (size_t)arow * Ie + sl * 8;
    }
#pragma unroll
    for (int i = 0; i < 4; ++i) {
        int r = wv * 32 + i * 8 + rowg;
        bg[i] = We + (size_t)r * Ie + sl * 8;
    }

    f32x4 acc[2][4];
#pragma unroll
    for (int i = 0; i < 2; ++i)
#pragma unroll
        for (int j = 0; j < 4; ++j) acc[i][j] = (f32x4)(0.f);

    int q = lane >> 4, m = lane & 15;
    int sw = m & 7;

    for (int k0 = 0; k0 < Ie; k0 += TK) {
#pragma unroll
        for (int i = 0; i < 2; ++i)
            ld16(ag[i] + k0, &As[(wv * 16 + i * 8) * TK]);
#pragma unroll
        for (int i = 0; i < 4; ++i)
            ld16(bg[i] + k0, &Bs[(wv * 32 + i * 8) * TK]);
        __syncthreads();
#pragma unroll
        for (int ks = 0; ks < TK; ks += 32) {
            int kc = ks >> 3;
            int ck = ((kc + q) ^ sw) << 3;
            bf16x8 af[2], bfr[4];
#pragma unroll
            for (int im = 0; im < 2; ++im)
                af[im] = *(const bf16x8*)&As[(wm + m + im * 16) * TK + ck];
#pragma unroll
            for (int in_ = 0; in_ < 4; ++in_)
                bfr[in_] = *(const bf16x8*)&Bs[(wn + m + in_ * 16) * TK + ck];
#pragma unroll
            for (int im = 0; im < 2; ++im)
#pragma unroll
                for (int in_ = 0; in_ < 4; ++in_)
                    acc[im][in_] = __builtin_amdgcn_mfma_f32_16x16x32_bf16(
                        af[im], bfr[in_], acc[im][in_], 0, 0, 0);
        }
        __syncthreads();
    }

#pragma unroll
    for (int im = 0; im < 2; ++im) {
#pragma unroll
        for (int j = 0; j < 4; ++j) {
            int row = wm + im * 16 + q * 4 + j;
            int gr = m0 + row;
            if (gr < cnt) {
                int tok = list[e * N + gr];
                float* orow = OUT + (size_t)tok * H + n0;
#pragma unroll
                for (int in_ = 0; in_ < 4; ++in_) {
                    int col = wn + in_ * 16 + m;
                    orow[col] = acc[im][in_][j];
                }
            }
        }
    }
}

extern "C" void kernel_launch(void* const* d_in, const int* in_sizes, int n_in,
                              void* d_out, int out_size, void* d_ws, size_t ws_size,
                              hipStream_t stream) {
    const float* hidden   = (const float*)d_in[0];
    const int*   tok_ids  = (const int*)d_in[1];
    const float* mu       = (const float*)d_in[2];
    const float* gup      = (const float*)d_in[3];
    const float* dnp      = (const float*)d_in[4];
    const float* rw       = (const float*)d_in[5];
    float* out = (float*)d_out;

    int N  = in_sizes[1];                 // 8192
    int H  = in_sizes[0] / N;             // 1024
    int E  = in_sizes[5] / H;             // 8
    int F2 = in_sizes[3] / (E * H);       // 1024
    int Ie = F2 / 2;                      // 512

    int NB = (N + 255) / 256;             // 32

    char* ws = (char*)d_ws;
    size_t o = 0;
    auto alloc = [&](size_t sz) {
        size_t r = o;
        o += (sz + 255) & ~(size_t)255;
        return r;
    };
    int* counts   = (int*)(ws + alloc((size_t)E * 4));
    int* base_    = (int*)(ws + alloc((size_t)E * 4));
    int* eids     = (int*)(ws + alloc((size_t)N * 4));
    int* blockcnt = (int*)(ws + alloc((size_t)NB * 8 * 4));
    int* offs     = (int*)(ws + alloc((size_t)NB * 8 * 4));
    int* list     = (int*)(ws + alloc((size_t)E * N * 4));
    unsigned short* xb   = (unsigned short*)(ws + alloc((size_t)N * H * 2));
    unsigned short* wgut = (unsigned short*)(ws + alloc((size_t)E * F2 * H * 2));
    unsigned short* wdnt = (unsigned short*)(ws + alloc((size_t)E * H * Ie * 2));
    unsigned short* it   = (unsigned short*)(ws + alloc((size_t)N * Ie * 2));

    k_convert_bf16<<<dim3((N * H / 4 + 255) / 256), dim3(256), 0, stream>>>(hidden, xb, N * H);

    dim3 tb(32, 8);
    k_transpose_bf16<<<dim3(F2 / 32, H / 32, E), tb, 0, stream>>>(gup, wgut, H, F2);
    k_transpose_bf16<<<dim3(H / 32, Ie / 32, E), tb, 0, stream>>>(dnp, wdnt, Ie, H);

    k_logits<<<dim3((N + 3) / 4), dim3(256), 0, stream>>>(mu, tok_ids, rw, H, N, eids);
    k_count<<<dim3(NB), dim3(256), 0, stream>>>(eids, blockcnt, N);
    k_scan<<<dim3(1), dim3(64), 0, stream>>>(blockcnt, counts, base_, offs, NB);
    k_scatter<<<dim3(NB), dim3(256), 0, stream>>>(eids, offs, list, N);

    int MT = (N + TM - 1) / TM;           // 128
    // flat XCD-pinned grids: bid&7 = expert
    k_gemm_gateup<<<dim3(E * MT * (Ie / 64)), dim3(256), 0, stream>>>(
        xb, wgut, it, counts, base_, list, N, H, Ie);

    k_gemm_down<<<dim3(E * MT * (H / TN)), dim3(256), 0, stream>>>(
        it, wdnt, out, counts, base_, list, N, Ie, H);
}

// Round 7
// 224.942 us; speedup vs baseline: 1.5455x; 1.0116x over previous
//
#include <hip/hip_runtime.h>
#include <hip/hip_bf16.h>
#include <stdint.h>

typedef __bf16 bf16x8 __attribute__((ext_vector_type(8)));
typedef float f32x4 __attribute__((ext_vector_type(4)));

#define ROUTE_BIAS_F 10.0f
#define VOCAB_SZ 32000

// ---------- helpers ----------
__device__ __forceinline__ unsigned short f2bf(float f) {
    union { float f; unsigned u; } v; v.f = f;
    unsigned u = v.u;
    unsigned r = u + 0x7FFFu + ((u >> 16) & 1u);   // RNE
    return (unsigned short)(r >> 16);
}
__device__ __forceinline__ float bf2f(unsigned short s) {
    union { unsigned u; float f; } v; v.u = ((unsigned)s) << 16;
    return v.f;
}
// async 16B global->LDS copy (lds dest wave-uniform; HW adds lane*16)
__device__ __forceinline__ void ld16(const unsigned short* g, unsigned short* l) {
    __builtin_amdgcn_global_load_lds(
        (const __attribute__((address_space(1))) void*)g,
        (__attribute__((address_space(3))) void*)l, 16, 0, 0);
}

// ---------- fused: hidden fp32->bf16 convert + router logits/argmax ----------
// one wave per token: convert 1024 floats AND compute 8 logits.
__global__ void k_prep(const float* __restrict__ hidden, const float* __restrict__ mu,
                       const int* __restrict__ tok_ids, const float* __restrict__ rw,
                       unsigned short* __restrict__ xb, int* __restrict__ eids,
                       int H, int N) {
    int lane = threadIdx.x & 63;
    int wv   = threadIdx.x >> 6;
    int tok  = blockIdx.x * 4 + wv;
    if (tok >= N) return;
    const float4* hp = (const float4*)(hidden + (size_t)tok * H);
    const float4* mp = (const float4*)(mu + (size_t)tok * H);
    const float4* rp = (const float4*)rw;            // [8][H/4]
    ushort4* xp = (ushort4*)(xb + (size_t)tok * H);
    int H4 = H >> 2;                                 // 256
    float acc[8];
#pragma unroll
    for (int e = 0; e < 8; ++e) acc[e] = 0.f;
#pragma unroll
    for (int j = 0; j < 4; ++j) {                    // H4/64 = 4
        int idx = lane + 64 * j;
        float4 h4 = hp[idx];
        ushort4 o;
        o.x = f2bf(h4.x); o.y = f2bf(h4.y); o.z = f2bf(h4.z); o.w = f2bf(h4.w);
        xp[idx] = o;
        float4 m4 = mp[idx];
#pragma unroll
        for (int e = 0; e < 8; ++e) {
            float4 w4 = rp[e * H4 + idx];
            acc[e] += m4.x * w4.x + m4.y * w4.y + m4.z * w4.z + m4.w * w4.w;
        }
    }
#pragma unroll
    for (int e = 0; e < 8; ++e) {
        float v = acc[e];
#pragma unroll
        for (int off = 32; off > 0; off >>= 1) v += __shfl_xor(v, off);
        acc[e] = v;
    }
    if (lane == 0) {
        int t = tok_ids[tok];
        if (t < 0) t = 0;
        if (t > VOCAB_SZ - 1) t = VOCAB_SZ - 1;
        int be = t % 8;
        float best = -1e30f; int bi = 0;
#pragma unroll
        for (int e = 0; e < 8; ++e) {
            float v = acc[e] + (e == be ? ROUTE_BIAS_F : 0.f);
            if (v > best) { best = v; bi = e; }
        }
        eids[tok] = bi;
    }
}

// ---------- merged per-expert transpose+convert for BOTH weights ----------
// z 0..7: gup expert z (R=H, C=F2); z 8..15: dnp expert z-8 (R=Ie, C=H).
__global__ void k_transpose_all(const float* __restrict__ gup, const float* __restrict__ dnp,
                                unsigned short* __restrict__ wgut, unsigned short* __restrict__ wdnt,
                                int H, int F2, int Ie) {
    __shared__ float tile[32][33];
    int z = blockIdx.z;
    const float* inp; unsigned short* outp; int R, C;
    if (z < 8) { R = H; C = F2; inp = gup + (size_t)z * R * C;       outp = wgut + (size_t)z * R * C; }
    else       { R = Ie; C = H; inp = dnp + (size_t)(z - 8) * R * C; outp = wdnt + (size_t)(z - 8) * R * C; }
    int c0 = blockIdx.x * 32, r0 = blockIdx.y * 32;
    if (r0 >= R || c0 >= C) return;
    int tx = threadIdx.x, ty = threadIdx.y;   // 32 x 8
#pragma unroll
    for (int k = 0; k < 32; k += 8)
        tile[ty + k][tx] = inp[(size_t)(r0 + ty + k) * C + c0 + tx];
    __syncthreads();
#pragma unroll
    for (int k = 0; k < 32; k += 8)
        outp[(size_t)(c0 + ty + k) * R + r0 + tx] = f2bf(tile[tx][ty + k]);
}

// ---------- router phase B: parallel counting sort ----------
__global__ void k_count(const int* __restrict__ eids,
                        int* __restrict__ blockcnt, int N) {
    __shared__ int cnt[8];
    int tid = threadIdx.x;
    if (tid < 8) cnt[tid] = 0;
    __syncthreads();
    int tok = blockIdx.x * 256 + tid;
    int lane = tid & 63;
    int eid = (tok < N) ? eids[tok] : -1;
#pragma unroll
    for (int e = 0; e < 8; ++e) {
        unsigned long long m = __ballot(eid == e);
        if (lane == 0 && m) atomicAdd(&cnt[e], __popcll(m));
    }
    __syncthreads();
    if (tid < 8) blockcnt[blockIdx.x * 8 + tid] = cnt[tid];
}

__global__ void k_scan(const int* __restrict__ blockcnt,
                       int* __restrict__ counts, int* __restrict__ base_,
                       int* __restrict__ offs, int NB) {   // NB == 32
    __shared__ int tot[8];
    int lane = threadIdx.x;
    int e = lane >> 3, g = lane & 7;
    int v[4];
    int s = 0;
#pragma unroll
    for (int i = 0; i < 4; ++i) { v[i] = s; s += blockcnt[(g * 4 + i) * 8 + e]; }
    int inc = s;
#pragma unroll
    for (int d = 1; d < 8; d <<= 1) {
        int t = __shfl_up(inc, d);
        if (g >= d) inc += t;
    }
    int excl = inc - s;
#pragma unroll
    for (int i = 0; i < 4; ++i) offs[(g * 4 + i) * 8 + e] = excl + v[i];
    if (g == 7) { counts[e] = inc; tot[e] = inc; }
    __syncthreads();
    if (lane == 0) {
        int s2 = 0;
#pragma unroll
        for (int i = 0; i < 8; ++i) { base_[i] = s2; s2 += tot[i]; }
    }
}

__global__ void k_scatter(const int* __restrict__ eids,
                          const int* __restrict__ offs,
                          int* __restrict__ list, int N) {
    __shared__ int wavecnt[4][8];
    int tid = threadIdx.x;
    int lane = tid & 63, wv = tid >> 6;
    int tok = blockIdx.x * 256 + tid;
    int eid = (tok < N) ? eids[tok] : -1;
    unsigned long long below = (1ull << lane) - 1ull;
    int myrank = 0;
#pragma unroll
    for (int e = 0; e < 8; ++e) {
        unsigned long long m = __ballot(eid == e);
        if (lane == 0) wavecnt[wv][e] = __popcll(m);
        if (eid == e) myrank = __popcll(m & below);
    }
    __syncthreads();
    if (eid >= 0) {
        int pre = 0;
        for (int w = 0; w < wv; ++w) pre += wavecnt[w][eid];
        int pos = offs[blockIdx.x * 8 + eid] + pre + myrank;
        list[eid * N + pos] = tok;
    }
}

// ---------- GEMM tile constants ----------
#define TM 64
#define TN 128
#define TK 64
// 128-thread blocks, 2 waves, each wave owns a 64x64 output tile (max frag
// reuse: 16KB LDS read per 524 KFLOP). LDS 24KB, 4 active blocks/CU.
// XOR chunk swizzle on global side keeps frag ds_read_b128 at <=2-way aliasing.

// GEMM1 fused: IT[compact_row][Ie] = silu(gate)*up of gather(X) @ Wgu^T.
// B-tile rows interleave gate/up: tile row 2c = gate col (nt*64+c), 2c+1 = up.
__global__ __launch_bounds__(128, 3) void k_gemm_gateup(
    const unsigned short* __restrict__ X,    // [N][H] bf16
    const unsigned short* __restrict__ Wt,   // [E][F2][H] bf16 (f-major)
    unsigned short* __restrict__ IT,         // [N][Ie] bf16 compact rows
    const int* __restrict__ counts, const int* __restrict__ base_,
    const int* __restrict__ list, int N, int H, int Ie) {
    int bid = blockIdx.x;
    int e = bid & 7;                 // XCD-pinned expert
    int t = bid >> 3;
    int nt = t & 7;                  // 8 n-tiles of 64 out cols (128 interleaved)
    int mt = t >> 3;
    int cnt = counts[e];
    int m0 = mt * TM;
    if (m0 >= cnt) return;
    int F2 = 2 * Ie;

    __shared__ __align__(16) unsigned short As[TM * TK];   // 8 KB
    __shared__ __align__(16) unsigned short Bs[TN * TK];   // 16 KB

    int tid = threadIdx.x;
    int lane = tid & 63, wv = tid >> 6;   // 2 waves
    int wn = wv * 64;

    int rowg = lane >> 3;            // 0..7 row within 8-row group
    int sl   = (lane & 7) ^ rowg;    // swizzled source chunk for staging

    const unsigned short* ag[4];
    const unsigned short* bg[8];
#pragma unroll
    for (int i = 0; i < 4; ++i) {
        int r = wv * 32 + i * 8 + rowg;          // A tile row 0..63
        int gr = m0 + r;
        int tokrow = (gr < cnt) ? list[e * N + gr] : 0;
        ag[i] = X + (size_t)tokrow * H + sl * 8;
    }
#pragma unroll
    for (int i = 0; i < 8; ++i) {
        int r = wv * 64 + i * 8 + rowg;          // B tile row 0..127
        int wrow = (r & 1) * Ie + nt * 64 + (r >> 1);
        bg[i] = Wt + ((size_t)e * F2 + wrow) * H + sl * 8;
    }

    f32x4 acc[4][4];
#pragma unroll
    for (int i = 0; i < 4; ++i)
#pragma unroll
        for (int j = 0; j < 4; ++j) acc[i][j] = (f32x4)(0.f);

    int q = lane >> 4, m = lane & 15;
    int sw = m & 7;

    for (int k0 = 0; k0 < H; k0 += TK) {
#pragma unroll
        for (int i = 0; i < 4; ++i)
            ld16(ag[i] + k0, &As[(wv * 32 + i * 8) * TK]);
#pragma unroll
        for (int i = 0; i < 8; ++i)
            ld16(bg[i] + k0, &Bs[(wv * 64 + i * 8) * TK]);
        __syncthreads();
#pragma unroll
        for (int ks = 0; ks < TK; ks += 32) {
            int kc = ks >> 3;
            int ck = ((kc + q) ^ sw) << 3;
            bf16x8 af[4], bfr[4];
#pragma unroll
            for (int im = 0; im < 4; ++im)
                af[im] = *(const bf16x8*)&As[(m + im * 16) * TK + ck];
#pragma unroll
            for (int in_ = 0; in_ < 4; ++in_)
                bfr[in_] = *(const bf16x8*)&Bs[(wn + m + in_ * 16) * TK + ck];
#pragma unroll
            for (int im = 0; im < 4; ++im)
#pragma unroll
                for (int in_ = 0; in_ < 4; ++in_)
                    acc[im][in_] = __builtin_amdgcn_mfma_f32_16x16x32_bf16(
                        af[im], bfr[in_], acc[im][in_], 0, 0, 0);
        }
        __syncthreads();
    }

    // epilogue: pair even(gate)/odd(up) lanes, silu in fp32, write IT
    int b = base_[e];
    int nt64 = nt * 64;
#pragma unroll
    for (int im = 0; im < 4; ++im) {
#pragma unroll
        for (int j = 0; j < 4; ++j) {
            int row = im * 16 + q * 4 + j;
            int gr = m0 + row;
#pragma unroll
            for (int in_ = 0; in_ < 4; ++in_) {
                float v = acc[im][in_][j];
                float u = __shfl_xor(v, 1);
                float g = v;
                float s = g / (1.f + __expf(-g));
                float res = s * u;
                if (!(lane & 1) && gr < cnt) {
                    int oc = nt64 + ((wn + in_ * 16 + m) >> 1);
                    IT[(size_t)(b + gr) * Ie + oc] = f2bf(res);
                }
            }
        }
    }
}

// GEMM2: OUT[token][H] = IT[compact_row][Ie] @ Wd^T, rows scattered by list
__global__ __launch_bounds__(128, 3) void k_gemm_down(
    const unsigned short* __restrict__ IT,   // [N][Ie] bf16 compact
    const unsigned short* __restrict__ Wt,   // [E][H][Ie] bf16 (h-major)
    float* __restrict__ OUT,                 // [N][H] fp32 token-order
    const int* __restrict__ counts, const int* __restrict__ base_,
    const int* __restrict__ list, int N, int Ie, int H) {
    int bid = blockIdx.x;
    int e = bid & 7;                 // XCD-pinned expert
    int t = bid >> 3;
    int nt = t & 7;                  // H/TN = 8
    int mt = t >> 3;
    int cnt = counts[e];
    int m0 = mt * TM;
    if (m0 >= cnt) return;
    int n0 = nt * TN;
    int b = base_[e];

    __shared__ __align__(16) unsigned short As[TM * TK];
    __shared__ __align__(16) unsigned short Bs[TN * TK];

    int tid = threadIdx.x;
    int lane = tid & 63, wv = tid >> 6;
    int wn = wv * 64;

    int rowg = lane >> 3;
    int sl   = (lane & 7) ^ rowg;

    const unsigned short* We = Wt + ((size_t)e * H + n0) * Ie;
    const unsigned short* ag[4];
    const unsigned short* bg[8];
#pragma unroll
    for (int i = 0; i < 4; ++i) {
        int r = wv * 32 + i * 8 + rowg;
        int gr = m0 + r;
        int arow = (gr < cnt) ? (b + gr) : b;
        ag[i] = IT + (size_t)arow * Ie + sl * 8;
    }
#pragma unroll
    for (int i = 0; i < 8; ++i) {
        int r = wv * 64 + i * 8 + rowg;
        bg[i] = We + (size_t)r * Ie + sl * 8;
    }

    f32x4 acc[4][4];
#pragma unroll
    for (int i = 0; i < 4; ++i)
#pragma unroll
        for (int j = 0; j < 4; ++j) acc[i][j] = (f32x4)(0.f);

    int q = lane >> 4, m = lane & 15;
    int sw = m & 7;

    for (int k0 = 0; k0 < Ie; k0 += TK) {
#pragma unroll
        for (int i = 0; i < 4; ++i)
            ld16(ag[i] + k0, &As[(wv * 32 + i * 8) * TK]);
#pragma unroll
        for (int i = 0; i < 8; ++i)
            ld16(bg[i] + k0, &Bs[(wv * 64 + i * 8) * TK]);
        __syncthreads();
#pragma unroll
        for (int ks = 0; ks < TK; ks += 32) {
            int kc = ks >> 3;
            int ck = ((kc + q) ^ sw) << 3;
            bf16x8 af[4], bfr[4];
#pragma unroll
            for (int im = 0; im < 4; ++im)
                af[im] = *(const bf16x8*)&As[(m + im * 16) * TK + ck];
#pragma unroll
            for (int in_ = 0; in_ < 4; ++in_)
                bfr[in_] = *(const bf16x8*)&Bs[(wn + m + in_ * 16) * TK + ck];
#pragma unroll
            for (int im = 0; im < 4; ++im)
#pragma unroll
                for (int in_ = 0; in_ < 4; ++in_)
                    acc[im][in_] = __builtin_amdgcn_mfma_f32_16x16x32_bf16(
                        af[im], bfr[in_], acc[im][in_], 0, 0, 0);
        }
        __syncthreads();
    }

#pragma unroll
    for (int im = 0; im < 4; ++im) {
#pragma unroll
        for (int j = 0; j < 4; ++j) {
            int row = im * 16 + q * 4 + j;
            int gr = m0 + row;
            if (gr < cnt) {
                int tok = list[e * N + gr];
                float* orow = OUT + (size_t)tok * H + n0;
#pragma unroll
                for (int in_ = 0; in_ < 4; ++in_) {
                    int col = wn + in_ * 16 + m;
                    orow[col] = acc[im][in_][j];
                }
            }
        }
    }
}

extern "C" void kernel_launch(void* const* d_in, const int* in_sizes, int n_in,
                              void* d_out, int out_size, void* d_ws, size_t ws_size,
                              hipStream_t stream) {
    const float* hidden   = (const float*)d_in[0];
    const int*   tok_ids  = (const int*)d_in[1];
    const float* mu       = (const float*)d_in[2];
    const float* gup      = (const float*)d_in[3];
    const float* dnp      = (const float*)d_in[4];
    const float* rw       = (const float*)d_in[5];
    float* out = (float*)d_out;

    int N  = in_sizes[1];                 // 8192
    int H  = in_sizes[0] / N;             // 1024
    int E  = in_sizes[5] / H;             // 8
    int F2 = in_sizes[3] / (E * H);       // 1024
    int Ie = F2 / 2;                      // 512

    int NB = (N + 255) / 256;             // 32

    char* ws = (char*)d_ws;
    size_t o = 0;
    auto alloc = [&](size_t sz) {
        size_t r = o;
        o += (sz + 255) & ~(size_t)255;
        return r;
    };
    int* counts   = (int*)(ws + alloc((size_t)E * 4));
    int* base_    = (int*)(ws + alloc((size_t)E * 4));
    int* eids     = (int*)(ws + alloc((size_t)N * 4));
    int* blockcnt = (int*)(ws + alloc((size_t)NB * 8 * 4));
    int* offs     = (int*)(ws + alloc((size_t)NB * 8 * 4));
    int* list     = (int*)(ws + alloc((size_t)E * N * 4));
    unsigned short* xb   = (unsigned short*)(ws + alloc((size_t)N * H * 2));
    unsigned short* wgut = (unsigned short*)(ws + alloc((size_t)E * F2 * H * 2));
    unsigned short* wdnt = (unsigned short*)(ws + alloc((size_t)E * H * Ie * 2));
    unsigned short* it   = (unsigned short*)(ws + alloc((size_t)N * Ie * 2));

    k_prep<<<dim3((N + 3) / 4), dim3(256), 0, stream>>>(hidden, mu, tok_ids, rw, xb, eids, H, N);

    k_transpose_all<<<dim3(32, 32, 16), dim3(32, 8), 0, stream>>>(gup, dnp, wgut, wdnt, H, F2, Ie);

    k_count<<<dim3(NB), dim3(256), 0, stream>>>(eids, blockcnt, N);
    k_scan<<<dim3(1), dim3(64), 0, stream>>>(blockcnt, counts, base_, offs, NB);
    k_scatter<<<dim3(NB), dim3(256), 0, stream>>>(eids, offs, list, N);

    int MT = (N + TM - 1) / TM;           // 128
    // flat XCD-pinned grids: bid&7 = expert
    k_gemm_gateup<<<dim3(E * MT * (Ie / 64)), dim3(128), 0, stream>>>(
        xb, wgut, it, counts, base_, list, N, H, Ie);

    k_gemm_down<<<dim3(E * MT * (H / TN)), dim3(128), 0, stream>>>(
        it, wdnt, out, counts, base_, list, N, Ie, H);
}